// Round 1
// baseline (1232.456 us; speedup 1.0000x reference)
//
#include <hip/hip_runtime.h>
#include <climits>

#define N_ 16384
#define C_ 16
#define H_ 256
#define W_ 704
#define HW_ (H_*W_)
#define NC_ (N_*C_)
#define EPS_ 1e-3f
#define HDR_ 512

typedef unsigned long long ull;

// ---- workspace layout (float units) ----
// ints [0..5]: sum_y, sum_x, min_y, max_y, min_x, max_x
// [8..23] ksum   [24..39] kssq
// [40..55] fcsum [56..71] fcssq
// [72..87] tsum  [88..103] tssq
// [104..119] fsum [120..135] fssq
// [136..151] kA  [152..167] kC
// [168..183] fcA [184..199] fcC
// [200..215] tA  [216..231] tC
// [232..247] fA  [248..263] fC
// [264] cy [265] cx [266] inv_mx_y [267] inv_mx_x
// arrays at HDR_: pts_lin(0) pos_lin(1) gath(2) t_lin(3) off(4,5) attn(6) neigh(7) f_lin(8) val(9..)

__device__ __forceinline__ float wsum64(float v){
#pragma unroll
  for (int o = 32; o > 0; o >>= 1) v += __shfl_down(v, o);
  return v;
}

#define LOAD16(dst, src) { const float4* _s=(const float4*)(src); float4 _a=_s[0],_b=_s[1],_c=_s[2],_d=_s[3]; \
  dst[0]=_a.x;dst[1]=_a.y;dst[2]=_a.z;dst[3]=_a.w; dst[4]=_b.x;dst[5]=_b.y;dst[6]=_b.z;dst[7]=_b.w; \
  dst[8]=_c.x;dst[9]=_c.y;dst[10]=_c.z;dst[11]=_c.w; dst[12]=_d.x;dst[13]=_d.y;dst[14]=_d.z;dst[15]=_d.w; }

#define STORE16(dst, src) { float4* _d=(float4*)(dst); \
  _d[0]=make_float4(src[0],src[1],src[2],src[3]); _d[1]=make_float4(src[4],src[5],src[6],src[7]); \
  _d[2]=make_float4(src[8],src[9],src[10],src[11]); _d[3]=make_float4(src[12],src[13],src[14],src[15]); }

__global__ void k_init(float* ws){
  int t = threadIdx.x;
  if (t == 0){
    int* ih = (int*)ws;
    ih[0]=0; ih[1]=0; ih[2]=INT_MAX; ih[3]=INT_MIN; ih[4]=INT_MAX; ih[5]=INT_MIN;
  }
  if (t < 128) ws[8+t] = 0.f;
}

__global__ __launch_bounds__(256) void k_gridstats(const int* __restrict__ grid, float* __restrict__ ws){
  int i = blockIdx.x*256 + threadIdx.x;
  int2 p = ((const int2*)grid)[i];
  int sy=p.x, sx=p.y, mny=p.x, mxy=p.x, mnx=p.y, mxx=p.y;
#pragma unroll
  for (int o=32;o>0;o>>=1){
    sy += __shfl_down(sy,o); sx += __shfl_down(sx,o);
    mny = min(mny,__shfl_down(mny,o)); mxy = max(mxy,__shfl_down(mxy,o));
    mnx = min(mnx,__shfl_down(mnx,o)); mxx = max(mxx,__shfl_down(mxx,o));
  }
  if ((threadIdx.x & 63) == 0){
    int* ih = (int*)ws;
    atomicAdd(&ih[0],sy); atomicAdd(&ih[1],sx);
    atomicMin(&ih[2],mny); atomicMax(&ih[3],mxy);
    atomicMin(&ih[4],mnx); atomicMax(&ih[5],mxx);
  }
}

__global__ void k_gridfin(float* ws){
  int* ih = (int*)ws;
  float cy = (float)ih[0] / (float)N_;
  float cx = (float)ih[1] / (float)N_;
  float my = fmaxf((float)ih[3]-cy, cy-(float)ih[2]);
  float mx = fmaxf((float)ih[5]-cx, cx-(float)ih[4]);
  if (my == 0.f) my = 1.f;
  if (mx == 0.f) mx = 1.f;
  ws[264]=cy; ws[265]=cx; ws[266]=1.f/my; ws[267]=1.f/mx;
}

__global__ __launch_bounds__(256) void k_lin1(
    const float* __restrict__ pf, const float* __restrict__ imf,
    const int* __restrict__ grid,
    const float* __restrict__ Wk, const float* __restrict__ bk,
    const float* __restrict__ Wfc, const float* __restrict__ bfc,
    float* __restrict__ ws)
{
  __shared__ float sWk[256], sbk[16], sWfc[32], sbfc[16];
  int t = threadIdx.x;
  sWk[t] = Wk[t];
  if (t < 16){ sbk[t]=bk[t]; sbfc[t]=bfc[t]; }
  if (t < 32) sWfc[t] = Wfc[t];
  __syncthreads();
  int i = blockIdx.x*256 + t;
  float p[16]; LOAD16(p, pf + i*16);
  float ok[16];
#pragma unroll
  for (int c=0;c<16;++c) ok[c] = sbk[c];
#pragma unroll
  for (int j=0;j<16;++j){ float v = p[j];
#pragma unroll
    for (int c=0;c<16;++c) ok[c] += v*sWk[j*16+c];
  }
  float* pts_lin = ws + HDR_;
  STORE16(pts_lin + i*16, ok);
  // pos
  float cy=ws[264], cx=ws[265], imy=ws[266], imx=ws[267];
  int2 g = ((const int2*)grid)[i];
  float ry = ((float)g.x - cy)*imy, rx = ((float)g.y - cx)*imx;
  float op[16];
#pragma unroll
  for (int c=0;c<16;++c) op[c] = ry*sWfc[c] + rx*sWfc[16+c] + sbfc[c];
  float* pos_lin = ws + HDR_ + NC_;
  STORE16(pos_lin + i*16, op);
  // gathered image features at grid point
  int pix = g.x*W_ + g.y;
  float gv[16];
#pragma unroll
  for (int c=0;c<16;++c) gv[c] = imf[c*HW_ + pix];
  float* gath = ws + HDR_ + 2*NC_;
  STORE16(gath + i*16, gv);
  // stats
  int lane = t & 63;
#pragma unroll
  for (int c=0;c<16;++c){
    float a = wsum64(ok[c]); float b = wsum64(ok[c]*ok[c]);
    if (lane==0){ atomicAdd(&ws[8+c], a); atomicAdd(&ws[24+c], b); }
    a = wsum64(op[c]); b = wsum64(op[c]*op[c]);
    if (lane==0){ atomicAdd(&ws[40+c], a); atomicAdd(&ws[56+c], b); }
  }
}

__global__ void k_bnfin(const float* __restrict__ g, const float* __restrict__ b,
                        float* __restrict__ ws, int sumOff, int aOff)
{
  int c = threadIdx.x;
  if (c >= 16) return;
  float mu  = ws[sumOff+c]   * (1.f/N_);
  float var = ws[sumOff+16+c]* (1.f/N_) - mu*mu;
  float a = g[c] / sqrtf(var + EPS_);
  ws[aOff+c]    = a;
  ws[aOff+16+c] = b[c] - mu*a;
}

__global__ __launch_bounds__(256) void k_qstage(
    const float* __restrict__ Wt, const float* __restrict__ bt,
    const float* __restrict__ Woff, const float* __restrict__ boff,
    const float* __restrict__ Wattn, const float* __restrict__ battn,
    float* __restrict__ ws)
{
  __shared__ float sWt[256], sWoff[512], sWattn[256];
  __shared__ float sbt[16], sboff[32], sbattn[16];
  __shared__ float skA[16], skC[16], sfcA[16], sfcC[16];
  int t = threadIdx.x;
  sWt[t]=Wt[t]; sWattn[t]=Wattn[t];
  sWoff[t]=Woff[t]; sWoff[t+256]=Woff[t+256];
  if (t<16){ sbt[t]=bt[t]; sbattn[t]=battn[t];
    skA[t]=ws[136+t]; skC[t]=ws[152+t]; sfcA[t]=ws[168+t]; sfcC[t]=ws[184+t]; }
  if (t<32) sboff[t]=boff[t];
  __syncthreads();
  int i = blockIdx.x*256 + t;
  float* pts_lin = ws + HDR_;
  float* pos_lin = ws + HDR_ + NC_;
  float* t_lin   = ws + HDR_ + 3*NC_;
  float* offp    = ws + HDR_ + 4*NC_;
  float* attnp   = ws + HDR_ + 6*NC_;
  float pl[16], po[16];
  LOAD16(pl, pts_lin + i*16);
  LOAD16(po, pos_lin + i*16);
  float pts[16], q[16];
#pragma unroll
  for (int c=0;c<16;++c){ pts[c] = pl[c]*skA[c]+skC[c]; q[c] = pts[c] + po[c]*sfcA[c]+sfcC[c]; }
  // t_lin = pts @ Wt + bt
  float tv[16];
#pragma unroll
  for (int c=0;c<16;++c) tv[c] = sbt[c];
#pragma unroll
  for (int j=0;j<16;++j){ float v=pts[j];
#pragma unroll
    for (int c=0;c<16;++c) tv[c] += v*sWt[j*16+c];
  }
  STORE16(t_lin + i*16, tv);
  int lane = t & 63;
#pragma unroll
  for (int c=0;c<16;++c){
    float a = wsum64(tv[c]); float b = wsum64(tv[c]*tv[c]);
    if (lane==0){ atomicAdd(&ws[72+c], a); atomicAdd(&ws[88+c], b); }
  }
  // off = q @ Woff + boff
  float ov[32];
#pragma unroll
  for (int o=0;o<32;++o) ov[o] = sboff[o];
#pragma unroll
  for (int j=0;j<16;++j){ float v=q[j];
#pragma unroll
    for (int o=0;o<32;++o) ov[o] += v*sWoff[j*32+o];
  }
  { float4* d=(float4*)(offp + i*32);
#pragma unroll
    for (int r=0;r<8;++r) d[r]=make_float4(ov[r*4],ov[r*4+1],ov[r*4+2],ov[r*4+3]);
  }
  // attn logits + per-head softmax (4 groups of 4)
  float l[16];
#pragma unroll
  for (int c=0;c<16;++c) l[c] = sbattn[c];
#pragma unroll
  for (int j=0;j<16;++j){ float v=q[j];
#pragma unroll
    for (int c=0;c<16;++c) l[c] += v*sWattn[j*16+c];
  }
  float av[16];
#pragma unroll
  for (int h=0;h<4;++h){
    float m = fmaxf(fmaxf(l[h*4],l[h*4+1]),fmaxf(l[h*4+2],l[h*4+3]));
    float e0=expf(l[h*4]-m), e1=expf(l[h*4+1]-m), e2=expf(l[h*4+2]-m), e3=expf(l[h*4+3]-m);
    float inv = 1.f/(e0+e1+e2+e3);
    av[h*4]=e0*inv; av[h*4+1]=e1*inv; av[h*4+2]=e2*inv; av[h*4+3]=e3*inv;
  }
  STORE16(attnp + i*16, av);
}

__global__ __launch_bounds__(256) void k_val(const float* __restrict__ imf,
    const float* __restrict__ Wval, const float* __restrict__ bval, float* __restrict__ ws)
{
  __shared__ float sW[256], sb[16];
  int t = threadIdx.x;
  sW[t] = Wval[t];
  if (t < 16) sb[t] = bval[t];
  __syncthreads();
  int pix = blockIdx.x*256 + t;
  float a[16];
#pragma unroll
  for (int ci=0;ci<16;++ci) a[ci] = imf[ci*HW_ + pix];
  float o[16];
#pragma unroll
  for (int c=0;c<16;++c) o[c] = sb[c];
#pragma unroll
  for (int ci=0;ci<16;++ci){ float v=a[ci];
#pragma unroll
    for (int c=0;c<16;++c) o[c] += v*sW[ci*16+c];
  }
  float* val = ws + HDR_ + 9*NC_;
  STORE16(val + pix*16, o);
}

#define TILE_ 2048
__global__ __launch_bounds__(256) void k_knn(const int* __restrict__ grid, float* __restrict__ ws)
{
  __shared__ int2 sP[TILE_];
  __shared__ ull  sK[256*9];
  __shared__ int  sNb[64*8];
  int tid = threadIdx.x;
  int s  = tid & 3;    // scanner id within point
  int pl = tid >> 2;   // local point 0..63
  int pi = blockIdx.x*64 + pl;
  int2 me = ((const int2*)grid)[pi];
  ull arr[9];
#pragma unroll
  for (int r=0;r<9;++r) arr[r] = ~0ull;
  for (int t0=0; t0<N_; t0+=TILE_){
    for (int j=tid; j<TILE_; j+=256) sP[j] = ((const int2*)grid)[t0+j];
    __syncthreads();
    for (int j=s; j<TILE_; j+=4){
      int2 pp = sP[j];
      int dy = me.x - pp.x, dx = me.y - pp.y;
      int d2 = dy*dy + dx*dx;
      ull key = ((ull)(unsigned)d2 << 14) | (unsigned)(t0+j);
      if (key < arr[8]){
        int q = 8;
        while (q > 0 && arr[q-1] > key){ arr[q] = arr[q-1]; --q; }
        arr[q] = key;
      }
    }
    __syncthreads();
  }
#pragma unroll
  for (int r=0;r<9;++r) sK[tid*9+r] = arr[r];
  __syncthreads();
  if (s == 0){
    for (int ss=1; ss<4; ++ss){
      for (int r=0; r<9; ++r){
        ull k = sK[(tid+ss)*9+r];
        if (k >= arr[8]) break;   // lists are sorted ascending
        int q = 8;
        while (q > 0 && arr[q-1] > k){ arr[q] = arr[q-1]; --q; }
        arr[q] = k;
      }
    }
#pragma unroll
    for (int r=1;r<9;++r) sNb[pl*8 + r-1] = (int)(arr[r] & (ull)(N_-1));
  }
  __syncthreads();
  const float* gath = ws + HDR_ + 2*NC_;
  float* neigh      = ws + HDR_ + 7*NC_;
  float4 acc = make_float4(0.f,0.f,0.f,0.f);
  for (int nb=0; nb<8; ++nb){
    const float4 g = *(const float4*)(gath + sNb[pl*8+nb]*16 + s*4);
    acc.x += g.x; acc.y += g.y; acc.z += g.z; acc.w += g.w;
  }
  *(float4*)(neigh + pi*16 + s*4) =
      make_float4(acc.x*0.125f, acc.y*0.125f, acc.z*0.125f, acc.w*0.125f);
}

__global__ __launch_bounds__(256) void k_attn(
    const int* __restrict__ grid,
    const float* __restrict__ Wout, const float* __restrict__ bout,
    const float* __restrict__ Wf, const float* __restrict__ bf,
    float* __restrict__ ws)
{
  __shared__ float sWout[256], sWf[512], sbout[16], sbf[16], stA[16], stC[16];
  int t = threadIdx.x;
  sWout[t]=Wout[t]; sWf[t]=Wf[t]; sWf[t+256]=Wf[t+256];
  if (t<16){ sbout[t]=bout[t]; sbf[t]=bf[t]; stA[t]=ws[200+t]; stC[t]=ws[216+t]; }
  __syncthreads();
  int i = blockIdx.x*256 + t;
  const float* t_lin  = ws + HDR_ + 3*NC_;
  const float* offp   = ws + HDR_ + 4*NC_;
  const float* attnp  = ws + HDR_ + 6*NC_;
  const float* neighp = ws + HDR_ + 7*NC_;
  float* f_lin        = ws + HDR_ + 8*NC_;
  const float4* val4  = (const float4*)(ws + HDR_ + 9*NC_);
  float offv[32];
  { const float4* s4=(const float4*)(offp + i*32);
#pragma unroll
    for (int r=0;r<8;++r){ float4 v=s4[r]; offv[r*4]=v.x; offv[r*4+1]=v.y; offv[r*4+2]=v.z; offv[r*4+3]=v.w; }
  }
  float av[16]; LOAD16(av, attnp + i*16);
  int2 g = ((const int2*)grid)[i];
  float y = (float)g.x, x = (float)g.y;
  float4 acc[4];
#pragma unroll
  for (int h=0;h<4;++h) acc[h]=make_float4(0.f,0.f,0.f,0.f);
#define CORNER(yy,xx,wgt) do{ int _y=(yy),_x=(xx); \
    if ((unsigned)_y < (unsigned)H_ && (unsigned)_x < (unsigned)W_){ \
      float4 _v = val4[(_y*W_+_x)*4 + h]; float _w = a*(wgt); \
      acc[h].x += _w*_v.x; acc[h].y += _w*_v.y; acc[h].z += _w*_v.z; acc[h].w += _w*_v.w; } }while(0)
#pragma unroll
  for (int h=0;h<4;++h){
#pragma unroll
    for (int p=0;p<4;++p){
      float a  = av[h*4+p];
      float ly = y + offv[h*8+p*2], lx = x + offv[h*8+p*2+1];
      float fy = floorf(ly), fx = floorf(lx);
      float wy = ly - fy, wx = lx - fx;
      int y0 = (int)fy, x0 = (int)fx;
      CORNER(y0,   x0,   (1.f-wy)*(1.f-wx));
      CORNER(y0,   x0+1, (1.f-wy)*wx);
      CORNER(y0+1, x0,   wy*(1.f-wx));
      CORNER(y0+1, x0+1, wy*wx);
    }
  }
#undef CORNER
  float o[16] = {acc[0].x,acc[0].y,acc[0].z,acc[0].w, acc[1].x,acc[1].y,acc[1].z,acc[1].w,
                 acc[2].x,acc[2].y,acc[2].z,acc[2].w, acc[3].x,acc[3].y,acc[3].z,acc[3].w};
  float nv[16]; LOAD16(nv, neighp + i*16);
  float img[16];
#pragma unroll
  for (int c=0;c<16;++c) img[c] = sbout[c] + nv[c];
#pragma unroll
  for (int j=0;j<16;++j){ float v=o[j];
#pragma unroll
    for (int c=0;c<16;++c) img[c] += v*sWout[j*16+c];
  }
  float tl[16]; LOAD16(tl, t_lin + i*16);
  float fuse[32];
#pragma unroll
  for (int c=0;c<16;++c) fuse[c]    = fmaxf(tl[c]*stA[c]+stC[c], 0.f);
#pragma unroll
  for (int c=0;c<16;++c) fuse[16+c] = fmaxf(img[c], 0.f);
  float fl[16];
#pragma unroll
  for (int c=0;c<16;++c) fl[c] = sbf[c];
#pragma unroll
  for (int j=0;j<32;++j){ float v=fuse[j];
#pragma unroll
    for (int c=0;c<16;++c) fl[c] += v*sWf[j*16+c];
  }
  STORE16(f_lin + i*16, fl);
  int lane = t & 63;
#pragma unroll
  for (int c=0;c<16;++c){
    float a = wsum64(fl[c]); float b = wsum64(fl[c]*fl[c]);
    if (lane==0){ atomicAdd(&ws[104+c], a); atomicAdd(&ws[120+c], b); }
  }
}

__global__ __launch_bounds__(256) void k_out(const float* __restrict__ ws, float* __restrict__ out){
  int idx = blockIdx.x*256 + threadIdx.x;
  int c = idx & 15;
  float v = ws[HDR_ + 8*NC_ + idx];
  out[idx] = fmaxf(v*ws[232+c] + ws[248+c], 0.f);
}

extern "C" void kernel_launch(void* const* d_in, const int* in_sizes, int n_in,
                              void* d_out, int out_size, void* d_ws, size_t ws_size,
                              hipStream_t stream)
{
  const float* pf    = (const float*)d_in[0];
  const float* imf   = (const float*)d_in[1];
  const int*   gridp = (const int*)d_in[2];
  const float* Wk   =(const float*)d_in[3],  *bk   =(const float*)d_in[4];
  const float* gk   =(const float*)d_in[5],  *betak=(const float*)d_in[6];
  const float* Wfc  =(const float*)d_in[7],  *bfc  =(const float*)d_in[8];
  const float* gfc  =(const float*)d_in[9],  *betafc=(const float*)d_in[10];
  const float* Wt   =(const float*)d_in[11], *bt   =(const float*)d_in[12];
  const float* gt   =(const float*)d_in[13], *betat=(const float*)d_in[14];
  const float* Woff =(const float*)d_in[15], *boff =(const float*)d_in[16];
  const float* Wattn=(const float*)d_in[17], *battn=(const float*)d_in[18];
  const float* Wval =(const float*)d_in[19], *bval =(const float*)d_in[20];
  const float* Wout =(const float*)d_in[21], *bout =(const float*)d_in[22];
  const float* Wf   =(const float*)d_in[23], *bf   =(const float*)d_in[24];
  const float* gf   =(const float*)d_in[25], *betaf=(const float*)d_in[26];
  float* ws  = (float*)d_ws;
  float* out = (float*)d_out;

  hipLaunchKernelGGL(k_init,      dim3(1),        dim3(128), 0, stream, ws);
  hipLaunchKernelGGL(k_gridstats, dim3(N_/256),   dim3(256), 0, stream, gridp, ws);
  hipLaunchKernelGGL(k_gridfin,   dim3(1),        dim3(1),   0, stream, ws);
  hipLaunchKernelGGL(k_lin1,      dim3(N_/256),   dim3(256), 0, stream, pf, imf, gridp, Wk, bk, Wfc, bfc, ws);
  hipLaunchKernelGGL(k_bnfin,     dim3(1),        dim3(16),  0, stream, gk, betak, ws, 8, 136);
  hipLaunchKernelGGL(k_bnfin,     dim3(1),        dim3(16),  0, stream, gfc, betafc, ws, 40, 168);
  hipLaunchKernelGGL(k_qstage,    dim3(N_/256),   dim3(256), 0, stream, Wt, bt, Woff, boff, Wattn, battn, ws);
  hipLaunchKernelGGL(k_bnfin,     dim3(1),        dim3(16),  0, stream, gt, betat, ws, 72, 200);
  hipLaunchKernelGGL(k_val,       dim3(HW_/256),  dim3(256), 0, stream, imf, Wval, bval, ws);
  hipLaunchKernelGGL(k_knn,       dim3(N_/64),    dim3(256), 0, stream, gridp, ws);
  hipLaunchKernelGGL(k_attn,      dim3(N_/256),   dim3(256), 0, stream, gridp, Wout, bout, Wf, bf, ws);
  hipLaunchKernelGGL(k_bnfin,     dim3(1),        dim3(16),  0, stream, gf, betaf, ws, 104, 232);
  hipLaunchKernelGGL(k_out,       dim3(NC_/256),  dim3(256), 0, stream, ws, out);
}

// Round 2
// 485.544 us; speedup vs baseline: 2.5383x; 2.5383x over previous
//
#include <hip/hip_runtime.h>
#include <climits>

#define N_ 16384
#define C_ 16
#define H_ 256
#define W_ 704
#define HW_ (H_*W_)
#define NC_ (N_*C_)
#define EPS_ 1e-3f
#define HDR_ 512

typedef unsigned long long ull;

// ---- workspace layout (float units) ----
// ints [0..5]: sum_y, sum_x, min_y, max_y, min_x, max_x
// [8..23] ksum   [24..39] kssq
// [40..55] fcsum [56..71] fcssq
// [72..87] tsum  [88..103] tssq
// [104..119] fsum [120..135] fssq
// [136..151] kA  [152..167] kC
// [168..183] fcA [184..199] fcC
// [200..215] tA  [216..231] tC
// [232..247] fA  [248..263] fC
// [264] cy [265] cx [266] inv_mx_y [267] inv_mx_x
// arrays at HDR_: pts_lin(0) pos_lin(1) gath(2) t_lin(3) off(4,5) attn(6) neigh(7) f_lin(8) val(9..)
// KNN int scratch after val: counts(180224) cellstart(180240) bsum(704) boff(704) psort(16384)

#define VAL_  (HDR_ + 9*NC_)
#define KNNI_ (VAL_ + HW_*16)

__device__ __forceinline__ float wsum64(float v){
#pragma unroll
  for (int o = 32; o > 0; o >>= 1) v += __shfl_down(v, o);
  return v;
}

#define LOAD16(dst, src) { const float4* _s=(const float4*)(src); float4 _a=_s[0],_b=_s[1],_c=_s[2],_d=_s[3]; \
  dst[0]=_a.x;dst[1]=_a.y;dst[2]=_a.z;dst[3]=_a.w; dst[4]=_b.x;dst[5]=_b.y;dst[6]=_b.z;dst[7]=_b.w; \
  dst[8]=_c.x;dst[9]=_c.y;dst[10]=_c.z;dst[11]=_c.w; dst[12]=_d.x;dst[13]=_d.y;dst[14]=_d.z;dst[15]=_d.w; }

#define STORE16(dst, src) { float4* _d=(float4*)(dst); \
  _d[0]=make_float4(src[0],src[1],src[2],src[3]); _d[1]=make_float4(src[4],src[5],src[6],src[7]); \
  _d[2]=make_float4(src[8],src[9],src[10],src[11]); _d[3]=make_float4(src[12],src[13],src[14],src[15]); }

__global__ void k_init(float* ws){
  int t = threadIdx.x;
  if (t == 0){
    int* ih = (int*)ws;
    ih[0]=0; ih[1]=0; ih[2]=INT_MAX; ih[3]=INT_MIN; ih[4]=INT_MAX; ih[5]=INT_MIN;
  }
  if (t < 128) ws[8+t] = 0.f;
}

__global__ __launch_bounds__(256) void k_gridstats(const int* __restrict__ grid, float* __restrict__ ws){
  int i = blockIdx.x*256 + threadIdx.x;
  int2 p = ((const int2*)grid)[i];
  int sy=p.x, sx=p.y, mny=p.x, mxy=p.x, mnx=p.y, mxx=p.y;
#pragma unroll
  for (int o=32;o>0;o>>=1){
    sy += __shfl_down(sy,o); sx += __shfl_down(sx,o);
    mny = min(mny,__shfl_down(mny,o)); mxy = max(mxy,__shfl_down(mxy,o));
    mnx = min(mnx,__shfl_down(mnx,o)); mxx = max(mxx,__shfl_down(mxx,o));
  }
  if ((threadIdx.x & 63) == 0){
    int* ih = (int*)ws;
    atomicAdd(&ih[0],sy); atomicAdd(&ih[1],sx);
    atomicMin(&ih[2],mny); atomicMax(&ih[3],mxy);
    atomicMin(&ih[4],mnx); atomicMax(&ih[5],mxx);
  }
}

__global__ void k_gridfin(float* ws){
  int* ih = (int*)ws;
  float cy = (float)ih[0] / (float)N_;
  float cx = (float)ih[1] / (float)N_;
  float my = fmaxf((float)ih[3]-cy, cy-(float)ih[2]);
  float mx = fmaxf((float)ih[5]-cx, cx-(float)ih[4]);
  if (my == 0.f) my = 1.f;
  if (mx == 0.f) mx = 1.f;
  ws[264]=cy; ws[265]=cx; ws[266]=1.f/my; ws[267]=1.f/mx;
}

// ---------- cell-binning for exact KNN ----------
__global__ __launch_bounds__(256) void k_zero(float* ws){
  int4* c = (int4*)(ws + KNNI_);
  c[blockIdx.x*256 + threadIdx.x] = make_int4(0,0,0,0);  // 176*256*4 = 180224
}

__global__ __launch_bounds__(256) void k_count(const int* __restrict__ grid, float* __restrict__ ws){
  int i = blockIdx.x*256 + threadIdx.x;
  int2 g = ((const int2*)grid)[i];
  int* counts = (int*)(ws + KNNI_);
  atomicAdd(&counts[g.x*W_ + g.y], 1);
}

__global__ __launch_bounds__(256) void k_scanA(float* ws){
  const int* counts = (const int*)(ws + KNNI_);
  int* bsum = (int*)(ws + KNNI_) + 180224 + 180240;
  int t = threadIdx.x;
  int v = counts[blockIdx.x*256 + t];
#pragma unroll
  for (int o=32;o>0;o>>=1) v += __shfl_down(v,o);
  __shared__ int w4[4];
  if ((t&63)==0) w4[t>>6] = v;
  __syncthreads();
  if (t==0) bsum[blockIdx.x] = w4[0]+w4[1]+w4[2]+w4[3];
}

__global__ __launch_bounds__(256) void k_scanB(float* ws){
  int* bsum = (int*)(ws + KNNI_) + 180224 + 180240;
  int* boff = bsum + 704;
  __shared__ int tmp[256];
  __shared__ int carry;
  int t = threadIdx.x;
  if (t==0) carry = 0;
  __syncthreads();
  for (int c=0;c<3;++c){
    int idx = c*256 + t;
    int v = (idx < 704) ? bsum[idx] : 0;
    tmp[t] = v;
    __syncthreads();
    for (int o=1;o<256;o<<=1){
      int x = (t>=o) ? tmp[t-o] : 0;
      __syncthreads();
      tmp[t] += x;
      __syncthreads();
    }
    int incl = tmp[t];
    int base = carry;
    if (idx < 704) boff[idx] = base + incl - v;
    __syncthreads();
    if (t==255) carry = base + incl;
    __syncthreads();
  }
}

__global__ __launch_bounds__(256) void k_scanC(float* ws){
  int* counts = (int*)(ws + KNNI_);
  int* cellst = counts + 180224;
  const int* boff = counts + 180224 + 180240 + 704;
  __shared__ int tmp[256];
  int t = threadIdx.x;
  int i = blockIdx.x*256 + t;
  int v = counts[i];
  tmp[t] = v;
  __syncthreads();
  for (int o=1;o<256;o<<=1){
    int x = (t>=o) ? tmp[t-o] : 0;
    __syncthreads();
    tmp[t] += x;
    __syncthreads();
  }
  int start = boff[blockIdx.x] + tmp[t] - v;
  cellst[i] = start;
  counts[i] = start;          // becomes the scatter cursor
  if (i == 0) cellst[HW_] = N_;
}

__global__ __launch_bounds__(256) void k_scatter(const int* __restrict__ grid, float* __restrict__ ws){
  int i = blockIdx.x*256 + threadIdx.x;
  int2 g = ((const int2*)grid)[i];
  int* counts = (int*)(ws + KNNI_);
  unsigned* psort = (unsigned*)(counts + 180224 + 180240 + 704 + 704);
  int pos = atomicAdd(&counts[g.x*W_ + g.y], 1);
  psort[pos] = ((unsigned)g.x<<24) | ((unsigned)g.y<<14) | (unsigned)i;
}

// exact KNN via expanding clipped box + fused neighbor-feature mean
__global__ __launch_bounds__(256) void k_knn2(const int* __restrict__ grid, float* __restrict__ ws){
  int i = blockIdx.x*256 + threadIdx.x;
  const int* cellst = (const int*)(ws + KNNI_) + 180224;
  const unsigned* psort = (const unsigned*)((const int*)(ws + KNNI_) + 180224 + 180240 + 704 + 704);
  int2 g = ((const int2*)grid)[i];
  int y = g.x, x = g.y;
  int r = 8;
  // pre-grow near borders so the clipped box holds enough candidates
  for (;;){
    int y0=max(y-r,0), y1=min(y+r,H_-1), x0=max(x-r,0), x1=min(x+r,W_-1);
    bool covered = (y0==0)&&(y1==H_-1)&&(x0==0)&&(x1==W_-1);
    int area = (y1-y0+1)*(x1-x0+1);
    if (area >= 224 || covered) break;
    r += 8;
  }
  ull arr[9];
  for (;;){
    int y0=max(y-r,0), y1=min(y+r,H_-1), x0=max(x-r,0), x1=min(x+r,W_-1);
    bool covered = (y0==0)&&(y1==H_-1)&&(x0==0)&&(x1==W_-1);
#pragma unroll
    for (int q=0;q<9;++q) arr[q] = ~0ull;
    for (int yy=y0; yy<=y1; ++yy){
      int rowb = yy*W_;
      int s = cellst[rowb + x0];
      int e = cellst[rowb + x1 + 1];
      for (int p=s; p<e; ++p){
        unsigned u = psort[p];
        int py = (int)(u>>24), px = (int)((u>>14)&1023), pi = (int)(u&16383);
        int dy = y-py, dx = x-px;
        int d2 = dy*dy + dx*dx;
        ull key = ((ull)(unsigned)d2 << 14) | (unsigned)pi;
        if (key < arr[8]){
          int q = 8;
          while (q > 0 && arr[q-1] > key){ arr[q] = arr[q-1]; --q; }
          arr[q] = key;
        }
      }
    }
    if (covered) break;
    if (arr[8] != ~0ull){
      int d9 = (int)(arr[8] >> 14);
      if (d9 < (r+1)*(r+1)) break;
    }
    r <<= 1;
  }
  // arr[0] is "self" slot (min d2, min index) — reference drops it; use arr[1..8]
  const float* gath = ws + HDR_ + 2*NC_;
  float acc[16];
#pragma unroll
  for (int c=0;c<16;++c) acc[c] = 0.f;
  for (int nb=1; nb<9; ++nb){
    int idx = (int)(arr[nb] & 16383ull);
    const float4* s4 = (const float4*)(gath + idx*16);
#pragma unroll
    for (int rq=0; rq<4; ++rq){
      float4 v = s4[rq];
      acc[rq*4]+=v.x; acc[rq*4+1]+=v.y; acc[rq*4+2]+=v.z; acc[rq*4+3]+=v.w;
    }
  }
  float* neigh = ws + HDR_ + 7*NC_;
  float o[16];
#pragma unroll
  for (int c=0;c<16;++c) o[c] = acc[c]*0.125f;
  STORE16(neigh + i*16, o);
}

__global__ __launch_bounds__(256) void k_lin1(
    const float* __restrict__ pf, const float* __restrict__ imf,
    const int* __restrict__ grid,
    const float* __restrict__ Wk, const float* __restrict__ bk,
    const float* __restrict__ Wfc, const float* __restrict__ bfc,
    float* __restrict__ ws)
{
  __shared__ float sWk[256], sbk[16], sWfc[32], sbfc[16];
  int t = threadIdx.x;
  sWk[t] = Wk[t];
  if (t < 16){ sbk[t]=bk[t]; sbfc[t]=bfc[t]; }
  if (t < 32) sWfc[t] = Wfc[t];
  __syncthreads();
  int i = blockIdx.x*256 + t;
  float p[16]; LOAD16(p, pf + i*16);
  float ok[16];
#pragma unroll
  for (int c=0;c<16;++c) ok[c] = sbk[c];
#pragma unroll
  for (int j=0;j<16;++j){ float v = p[j];
#pragma unroll
    for (int c=0;c<16;++c) ok[c] += v*sWk[j*16+c];
  }
  float* pts_lin = ws + HDR_;
  STORE16(pts_lin + i*16, ok);
  float cy=ws[264], cx=ws[265], imy=ws[266], imx=ws[267];
  int2 g = ((const int2*)grid)[i];
  float ry = ((float)g.x - cy)*imy, rx = ((float)g.y - cx)*imx;
  float op[16];
#pragma unroll
  for (int c=0;c<16;++c) op[c] = ry*sWfc[c] + rx*sWfc[16+c] + sbfc[c];
  float* pos_lin = ws + HDR_ + NC_;
  STORE16(pos_lin + i*16, op);
  int pix = g.x*W_ + g.y;
  float gv[16];
#pragma unroll
  for (int c=0;c<16;++c) gv[c] = imf[c*HW_ + pix];
  float* gath = ws + HDR_ + 2*NC_;
  STORE16(gath + i*16, gv);
  int lane = t & 63;
#pragma unroll
  for (int c=0;c<16;++c){
    float a = wsum64(ok[c]); float b = wsum64(ok[c]*ok[c]);
    if (lane==0){ atomicAdd(&ws[8+c], a); atomicAdd(&ws[24+c], b); }
    a = wsum64(op[c]); b = wsum64(op[c]*op[c]);
    if (lane==0){ atomicAdd(&ws[40+c], a); atomicAdd(&ws[56+c], b); }
  }
}

__global__ void k_bnfin(const float* __restrict__ g, const float* __restrict__ b,
                        float* __restrict__ ws, int sumOff, int aOff)
{
  int c = threadIdx.x;
  if (c >= 16) return;
  float mu  = ws[sumOff+c]   * (1.f/N_);
  float var = ws[sumOff+16+c]* (1.f/N_) - mu*mu;
  float a = g[c] / sqrtf(var + EPS_);
  ws[aOff+c]    = a;
  ws[aOff+16+c] = b[c] - mu*a;
}

__global__ __launch_bounds__(256) void k_qstage(
    const float* __restrict__ Wt, const float* __restrict__ bt,
    const float* __restrict__ Woff, const float* __restrict__ boff,
    const float* __restrict__ Wattn, const float* __restrict__ battn,
    float* __restrict__ ws)
{
  __shared__ float sWt[256], sWoff[512], sWattn[256];
  __shared__ float sbt[16], sboff[32], sbattn[16];
  __shared__ float skA[16], skC[16], sfcA[16], sfcC[16];
  int t = threadIdx.x;
  sWt[t]=Wt[t]; sWattn[t]=Wattn[t];
  sWoff[t]=Woff[t]; sWoff[t+256]=Woff[t+256];
  if (t<16){ sbt[t]=bt[t]; sbattn[t]=battn[t];
    skA[t]=ws[136+t]; skC[t]=ws[152+t]; sfcA[t]=ws[168+t]; sfcC[t]=ws[184+t]; }
  if (t<32) sboff[t]=boff[t];
  __syncthreads();
  int i = blockIdx.x*256 + t;
  float* pts_lin = ws + HDR_;
  float* pos_lin = ws + HDR_ + NC_;
  float* t_lin   = ws + HDR_ + 3*NC_;
  float* offp    = ws + HDR_ + 4*NC_;
  float* attnp   = ws + HDR_ + 6*NC_;
  float pl[16], po[16];
  LOAD16(pl, pts_lin + i*16);
  LOAD16(po, pos_lin + i*16);
  float pts[16], q[16];
#pragma unroll
  for (int c=0;c<16;++c){ pts[c] = pl[c]*skA[c]+skC[c]; q[c] = pts[c] + po[c]*sfcA[c]+sfcC[c]; }
  float tv[16];
#pragma unroll
  for (int c=0;c<16;++c) tv[c] = sbt[c];
#pragma unroll
  for (int j=0;j<16;++j){ float v=pts[j];
#pragma unroll
    for (int c=0;c<16;++c) tv[c] += v*sWt[j*16+c];
  }
  STORE16(t_lin + i*16, tv);
  int lane = t & 63;
#pragma unroll
  for (int c=0;c<16;++c){
    float a = wsum64(tv[c]); float b = wsum64(tv[c]*tv[c]);
    if (lane==0){ atomicAdd(&ws[72+c], a); atomicAdd(&ws[88+c], b); }
  }
  float ov[32];
#pragma unroll
  for (int o=0;o<32;++o) ov[o] = sboff[o];
#pragma unroll
  for (int j=0;j<16;++j){ float v=q[j];
#pragma unroll
    for (int o=0;o<32;++o) ov[o] += v*sWoff[j*32+o];
  }
  { float4* d=(float4*)(offp + i*32);
#pragma unroll
    for (int r=0;r<8;++r) d[r]=make_float4(ov[r*4],ov[r*4+1],ov[r*4+2],ov[r*4+3]);
  }
  float l[16];
#pragma unroll
  for (int c=0;c<16;++c) l[c] = sbattn[c];
#pragma unroll
  for (int j=0;j<16;++j){ float v=q[j];
#pragma unroll
    for (int c=0;c<16;++c) l[c] += v*sWattn[j*16+c];
  }
  float av[16];
#pragma unroll
  for (int h=0;h<4;++h){
    float m = fmaxf(fmaxf(l[h*4],l[h*4+1]),fmaxf(l[h*4+2],l[h*4+3]));
    float e0=expf(l[h*4]-m), e1=expf(l[h*4+1]-m), e2=expf(l[h*4+2]-m), e3=expf(l[h*4+3]-m);
    float inv = 1.f/(e0+e1+e2+e3);
    av[h*4]=e0*inv; av[h*4+1]=e1*inv; av[h*4+2]=e2*inv; av[h*4+3]=e3*inv;
  }
  STORE16(attnp + i*16, av);
}

__global__ __launch_bounds__(256) void k_val(const float* __restrict__ imf,
    const float* __restrict__ Wval, const float* __restrict__ bval, float* __restrict__ ws)
{
  __shared__ float sW[256], sb[16];
  int t = threadIdx.x;
  sW[t] = Wval[t];
  if (t < 16) sb[t] = bval[t];
  __syncthreads();
  int pix = blockIdx.x*256 + t;
  float a[16];
#pragma unroll
  for (int ci=0;ci<16;++ci) a[ci] = imf[ci*HW_ + pix];
  float o[16];
#pragma unroll
  for (int c=0;c<16;++c) o[c] = sb[c];
#pragma unroll
  for (int ci=0;ci<16;++ci){ float v=a[ci];
#pragma unroll
    for (int c=0;c<16;++c) o[c] += v*sW[ci*16+c];
  }
  float* val = ws + VAL_;
  STORE16(val + pix*16, o);
}

__global__ __launch_bounds__(256) void k_attn(
    const int* __restrict__ grid,
    const float* __restrict__ Wout, const float* __restrict__ bout,
    const float* __restrict__ Wf, const float* __restrict__ bf,
    float* __restrict__ ws)
{
  __shared__ float sWout[256], sWf[512], sbout[16], sbf[16], stA[16], stC[16];
  int t = threadIdx.x;
  sWout[t]=Wout[t]; sWf[t]=Wf[t]; sWf[t+256]=Wf[t+256];
  if (t<16){ sbout[t]=bout[t]; sbf[t]=bf[t]; stA[t]=ws[200+t]; stC[t]=ws[216+t]; }
  __syncthreads();
  int i = blockIdx.x*256 + t;
  const float* t_lin  = ws + HDR_ + 3*NC_;
  const float* offp   = ws + HDR_ + 4*NC_;
  const float* attnp  = ws + HDR_ + 6*NC_;
  const float* neighp = ws + HDR_ + 7*NC_;
  float* f_lin        = ws + HDR_ + 8*NC_;
  const float4* val4  = (const float4*)(ws + VAL_);
  float offv[32];
  { const float4* s4=(const float4*)(offp + i*32);
#pragma unroll
    for (int r=0;r<8;++r){ float4 v=s4[r]; offv[r*4]=v.x; offv[r*4+1]=v.y; offv[r*4+2]=v.z; offv[r*4+3]=v.w; }
  }
  float av[16]; LOAD16(av, attnp + i*16);
  int2 g = ((const int2*)grid)[i];
  float y = (float)g.x, x = (float)g.y;
  float4 acc[4];
#pragma unroll
  for (int h=0;h<4;++h) acc[h]=make_float4(0.f,0.f,0.f,0.f);
#define CORNER(yy,xx,wgt) do{ int _y=(yy),_x=(xx); \
    if ((unsigned)_y < (unsigned)H_ && (unsigned)_x < (unsigned)W_){ \
      float4 _v = val4[(_y*W_+_x)*4 + h]; float _w = a*(wgt); \
      acc[h].x += _w*_v.x; acc[h].y += _w*_v.y; acc[h].z += _w*_v.z; acc[h].w += _w*_v.w; } }while(0)
#pragma unroll
  for (int h=0;h<4;++h){
#pragma unroll
    for (int p=0;p<4;++p){
      float a  = av[h*4+p];
      float ly = y + offv[h*8+p*2], lx = x + offv[h*8+p*2+1];
      float fy = floorf(ly), fx = floorf(lx);
      float wy = ly - fy, wx = lx - fx;
      int y0 = (int)fy, x0 = (int)fx;
      CORNER(y0,   x0,   (1.f-wy)*(1.f-wx));
      CORNER(y0,   x0+1, (1.f-wy)*wx);
      CORNER(y0+1, x0,   wy*(1.f-wx));
      CORNER(y0+1, x0+1, wy*wx);
    }
  }
#undef CORNER
  float o[16] = {acc[0].x,acc[0].y,acc[0].z,acc[0].w, acc[1].x,acc[1].y,acc[1].z,acc[1].w,
                 acc[2].x,acc[2].y,acc[2].z,acc[2].w, acc[3].x,acc[3].y,acc[3].z,acc[3].w};
  float nv[16]; LOAD16(nv, neighp + i*16);
  float img[16];
#pragma unroll
  for (int c=0;c<16;++c) img[c] = sbout[c] + nv[c];
#pragma unroll
  for (int j=0;j<16;++j){ float v=o[j];
#pragma unroll
    for (int c=0;c<16;++c) img[c] += v*sWout[j*16+c];
  }
  float tl[16]; LOAD16(tl, t_lin + i*16);
  float fuse[32];
#pragma unroll
  for (int c=0;c<16;++c) fuse[c]    = fmaxf(tl[c]*stA[c]+stC[c], 0.f);
#pragma unroll
  for (int c=0;c<16;++c) fuse[16+c] = fmaxf(img[c], 0.f);
  float fl[16];
#pragma unroll
  for (int c=0;c<16;++c) fl[c] = sbf[c];
#pragma unroll
  for (int j=0;j<32;++j){ float v=fuse[j];
#pragma unroll
    for (int c=0;c<16;++c) fl[c] += v*sWf[j*16+c];
  }
  STORE16(f_lin + i*16, fl);
  int lane = t & 63;
#pragma unroll
  for (int c=0;c<16;++c){
    float a = wsum64(fl[c]); float b = wsum64(fl[c]*fl[c]);
    if (lane==0){ atomicAdd(&ws[104+c], a); atomicAdd(&ws[120+c], b); }
  }
}

__global__ __launch_bounds__(256) void k_out(const float* __restrict__ ws, float* __restrict__ out){
  int idx = blockIdx.x*256 + threadIdx.x;
  int c = idx & 15;
  float v = ws[HDR_ + 8*NC_ + idx];
  out[idx] = fmaxf(v*ws[232+c] + ws[248+c], 0.f);
}

extern "C" void kernel_launch(void* const* d_in, const int* in_sizes, int n_in,
                              void* d_out, int out_size, void* d_ws, size_t ws_size,
                              hipStream_t stream)
{
  const float* pf    = (const float*)d_in[0];
  const float* imf   = (const float*)d_in[1];
  const int*   gridp = (const int*)d_in[2];
  const float* Wk   =(const float*)d_in[3],  *bk   =(const float*)d_in[4];
  const float* gk   =(const float*)d_in[5],  *betak=(const float*)d_in[6];
  const float* Wfc  =(const float*)d_in[7],  *bfc  =(const float*)d_in[8];
  const float* gfc  =(const float*)d_in[9],  *betafc=(const float*)d_in[10];
  const float* Wt   =(const float*)d_in[11], *bt   =(const float*)d_in[12];
  const float* gt   =(const float*)d_in[13], *betat=(const float*)d_in[14];
  const float* Woff =(const float*)d_in[15], *boff =(const float*)d_in[16];
  const float* Wattn=(const float*)d_in[17], *battn=(const float*)d_in[18];
  const float* Wval =(const float*)d_in[19], *bval =(const float*)d_in[20];
  const float* Wout =(const float*)d_in[21], *bout =(const float*)d_in[22];
  const float* Wf   =(const float*)d_in[23], *bf   =(const float*)d_in[24];
  const float* gf   =(const float*)d_in[25], *betaf=(const float*)d_in[26];
  float* ws  = (float*)d_ws;
  float* out = (float*)d_out;

  hipLaunchKernelGGL(k_init,      dim3(1),        dim3(128), 0, stream, ws);
  hipLaunchKernelGGL(k_gridstats, dim3(N_/256),   dim3(256), 0, stream, gridp, ws);
  hipLaunchKernelGGL(k_gridfin,   dim3(1),        dim3(1),   0, stream, ws);
  hipLaunchKernelGGL(k_zero,      dim3(176),      dim3(256), 0, stream, ws);
  hipLaunchKernelGGL(k_count,     dim3(N_/256),   dim3(256), 0, stream, gridp, ws);
  hipLaunchKernelGGL(k_scanA,     dim3(704),      dim3(256), 0, stream, ws);
  hipLaunchKernelGGL(k_scanB,     dim3(1),        dim3(256), 0, stream, ws);
  hipLaunchKernelGGL(k_scanC,     dim3(704),      dim3(256), 0, stream, ws);
  hipLaunchKernelGGL(k_scatter,   dim3(N_/256),   dim3(256), 0, stream, gridp, ws);
  hipLaunchKernelGGL(k_lin1,      dim3(N_/256),   dim3(256), 0, stream, pf, imf, gridp, Wk, bk, Wfc, bfc, ws);
  hipLaunchKernelGGL(k_bnfin,     dim3(1),        dim3(16),  0, stream, gk, betak, ws, 8, 136);
  hipLaunchKernelGGL(k_bnfin,     dim3(1),        dim3(16),  0, stream, gfc, betafc, ws, 40, 168);
  hipLaunchKernelGGL(k_qstage,    dim3(N_/256),   dim3(256), 0, stream, Wt, bt, Woff, boff, Wattn, battn, ws);
  hipLaunchKernelGGL(k_bnfin,     dim3(1),        dim3(16),  0, stream, gt, betat, ws, 72, 200);
  hipLaunchKernelGGL(k_val,       dim3(HW_/256),  dim3(256), 0, stream, imf, Wval, bval, ws);
  hipLaunchKernelGGL(k_knn2,      dim3(N_/256),   dim3(256), 0, stream, gridp, ws);
  hipLaunchKernelGGL(k_attn,      dim3(N_/256),   dim3(256), 0, stream, gridp, Wout, bout, Wf, bf, ws);
  hipLaunchKernelGGL(k_bnfin,     dim3(1),        dim3(16),  0, stream, gf, betaf, ws, 104, 232);
  hipLaunchKernelGGL(k_out,       dim3(NC_/256),  dim3(256), 0, stream, ws, out);
}

// Round 3
// 473.660 us; speedup vs baseline: 2.6020x; 1.0251x over previous
//
#include <hip/hip_runtime.h>
#include <climits>

#define N_ 16384
#define C_ 16
#define H_ 256
#define W_ 704
#define HW_ (H_*W_)
#define NC_ (N_*C_)
#define EPS_ 1e-3f
#define HDR_ 512

typedef unsigned long long ull;

// ---- workspace layout (float units) ----
// ints [0..5]: sum_y, sum_x, min_y, max_y, min_x, max_x
// [8..23] ksum   [24..39] kssq
// [40..55] fcsum [56..71] fcssq
// [72..87] tsum  [88..103] tssq
// [104..119] fsum [120..135] fssq
// [136..151] kA  [152..167] kC
// [168..183] fcA [184..199] fcC
// [200..215] tA  [216..231] tC
// [232..247] fA  [248..263] fC
// [264] cy [265] cx [266] inv_mx_y [267] inv_mx_x
// arrays at HDR_: pts_lin(0) pos_lin(1) gath(2) t_lin(3) off(4,5) attn(6) neigh(7) f_lin(8) val(9..)
// KNN int scratch after val: counts(180224) cellstart(180240) bsum(704) boff(704) psort(16384)

#define VAL_  (HDR_ + 9*NC_)
#define KNNI_ (VAL_ + HW_*16)

__device__ __forceinline__ float wsum64(float v){
#pragma unroll
  for (int o = 32; o > 0; o >>= 1) v += __shfl_down(v, o);
  return v;
}

#define LOAD16(dst, src) { const float4* _s=(const float4*)(src); float4 _a=_s[0],_b=_s[1],_c=_s[2],_d=_s[3]; \
  dst[0]=_a.x;dst[1]=_a.y;dst[2]=_a.z;dst[3]=_a.w; dst[4]=_b.x;dst[5]=_b.y;dst[6]=_b.z;dst[7]=_b.w; \
  dst[8]=_c.x;dst[9]=_c.y;dst[10]=_c.z;dst[11]=_c.w; dst[12]=_d.x;dst[13]=_d.y;dst[14]=_d.z;dst[15]=_d.w; }

#define STORE16(dst, src) { float4* _d=(float4*)(dst); \
  _d[0]=make_float4(src[0],src[1],src[2],src[3]); _d[1]=make_float4(src[4],src[5],src[6],src[7]); \
  _d[2]=make_float4(src[8],src[9],src[10],src[11]); _d[3]=make_float4(src[12],src[13],src[14],src[15]); }

__global__ void k_init(float* ws){
  int t = threadIdx.x;
  if (t == 0){
    int* ih = (int*)ws;
    ih[0]=0; ih[1]=0; ih[2]=INT_MAX; ih[3]=INT_MIN; ih[4]=INT_MAX; ih[5]=INT_MIN;
  }
  if (t < 128) ws[8+t] = 0.f;
}

__global__ __launch_bounds__(256) void k_gridstats(const int* __restrict__ grid, float* __restrict__ ws){
  int i = blockIdx.x*256 + threadIdx.x;
  int2 p = ((const int2*)grid)[i];
  int sy=p.x, sx=p.y, mny=p.x, mxy=p.x, mnx=p.y, mxx=p.y;
#pragma unroll
  for (int o=32;o>0;o>>=1){
    sy += __shfl_down(sy,o); sx += __shfl_down(sx,o);
    mny = min(mny,__shfl_down(mny,o)); mxy = max(mxy,__shfl_down(mxy,o));
    mnx = min(mnx,__shfl_down(mnx,o)); mxx = max(mxx,__shfl_down(mxx,o));
  }
  if ((threadIdx.x & 63) == 0){
    int* ih = (int*)ws;
    atomicAdd(&ih[0],sy); atomicAdd(&ih[1],sx);
    atomicMin(&ih[2],mny); atomicMax(&ih[3],mxy);
    atomicMin(&ih[4],mnx); atomicMax(&ih[5],mxx);
  }
}

__global__ void k_gridfin(float* ws){
  int* ih = (int*)ws;
  float cy = (float)ih[0] / (float)N_;
  float cx = (float)ih[1] / (float)N_;
  float my = fmaxf((float)ih[3]-cy, cy-(float)ih[2]);
  float mx = fmaxf((float)ih[5]-cx, cx-(float)ih[4]);
  if (my == 0.f) my = 1.f;
  if (mx == 0.f) mx = 1.f;
  ws[264]=cy; ws[265]=cx; ws[266]=1.f/my; ws[267]=1.f/mx;
}

// ---------- cell-binning for exact KNN ----------
__global__ __launch_bounds__(256) void k_zero(float* ws){
  int4* c = (int4*)(ws + KNNI_);
  c[blockIdx.x*256 + threadIdx.x] = make_int4(0,0,0,0);
}

__global__ __launch_bounds__(256) void k_count(const int* __restrict__ grid, float* __restrict__ ws){
  int i = blockIdx.x*256 + threadIdx.x;
  int2 g = ((const int2*)grid)[i];
  int* counts = (int*)(ws + KNNI_);
  atomicAdd(&counts[g.x*W_ + g.y], 1);
}

__global__ __launch_bounds__(256) void k_scanA(float* ws){
  const int* counts = (const int*)(ws + KNNI_);
  int* bsum = (int*)(ws + KNNI_) + 180224 + 180240;
  int t = threadIdx.x;
  int v = counts[blockIdx.x*256 + t];
#pragma unroll
  for (int o=32;o>0;o>>=1) v += __shfl_down(v,o);
  __shared__ int w4[4];
  if ((t&63)==0) w4[t>>6] = v;
  __syncthreads();
  if (t==0) bsum[blockIdx.x] = w4[0]+w4[1]+w4[2]+w4[3];
}

__global__ __launch_bounds__(256) void k_scanB(float* ws){
  int* bsum = (int*)(ws + KNNI_) + 180224 + 180240;
  int* boff = bsum + 704;
  __shared__ int tmp[256];
  __shared__ int carry;
  int t = threadIdx.x;
  if (t==0) carry = 0;
  __syncthreads();
  for (int c=0;c<3;++c){
    int idx = c*256 + t;
    int v = (idx < 704) ? bsum[idx] : 0;
    tmp[t] = v;
    __syncthreads();
    for (int o=1;o<256;o<<=1){
      int x = (t>=o) ? tmp[t-o] : 0;
      __syncthreads();
      tmp[t] += x;
      __syncthreads();
    }
    int incl = tmp[t];
    int base = carry;
    if (idx < 704) boff[idx] = base + incl - v;
    __syncthreads();
    if (t==255) carry = base + incl;
    __syncthreads();
  }
}

__global__ __launch_bounds__(256) void k_scanC(float* ws){
  int* counts = (int*)(ws + KNNI_);
  int* cellst = counts + 180224;
  const int* boff = counts + 180224 + 180240 + 704;
  __shared__ int tmp[256];
  int t = threadIdx.x;
  int i = blockIdx.x*256 + t;
  int v = counts[i];
  tmp[t] = v;
  __syncthreads();
  for (int o=1;o<256;o<<=1){
    int x = (t>=o) ? tmp[t-o] : 0;
    __syncthreads();
    tmp[t] += x;
    __syncthreads();
  }
  int start = boff[blockIdx.x] + tmp[t] - v;
  cellst[i] = start;
  counts[i] = start;          // becomes the scatter cursor
  if (i == 0) cellst[HW_] = N_;
}

__global__ __launch_bounds__(256) void k_scatter(const int* __restrict__ grid, float* __restrict__ ws){
  int i = blockIdx.x*256 + threadIdx.x;
  int2 g = ((const int2*)grid)[i];
  int* counts = (int*)(ws + KNNI_);
  unsigned* psort = (unsigned*)(counts + 180224 + 180240 + 704 + 704);
  int pos = atomicAdd(&counts[g.x*W_ + g.y], 1);
  psort[pos] = ((unsigned)g.x<<24) | ((unsigned)g.y<<14) | (unsigned)i;
}

// wide gather: one thread per (point, channel)
__global__ __launch_bounds__(256) void k_gath(const float* __restrict__ imf,
                                              const int* __restrict__ grid,
                                              float* __restrict__ ws){
  int idx = blockIdx.x*256 + threadIdx.x;   // 0..262143
  int i = idx >> 4, c = idx & 15;
  int2 g = ((const int2*)grid)[i];
  ws[HDR_ + 2*NC_ + idx] = imf[c*HW_ + g.x*W_ + g.y];
}

// exact KNN (points processed in cell-sorted order for wave coherence)
__global__ __launch_bounds__(64) void k_knn2(float* __restrict__ ws){
  int gid = blockIdx.x*64 + threadIdx.x;
  const int* cellst = (const int*)(ws + KNNI_) + 180224;
  const unsigned* psort = (const unsigned*)((const int*)(ws + KNNI_) + 180224 + 180240 + 704 + 704);
  unsigned me = psort[gid];
  int y = (int)(me>>24), x = (int)((me>>14)&1023), i = (int)(me&16383);
  int r = 8;
  for (;;){
    int y0=max(y-r,0), y1=min(y+r,H_-1), x0=max(x-r,0), x1=min(x+r,W_-1);
    bool covered = (y0==0)&&(y1==H_-1)&&(x0==0)&&(x1==W_-1);
    int area = (y1-y0+1)*(x1-x0+1);
    if (area >= 224 || covered) break;
    r += 8;
  }
  ull arr[9];
  for (;;){
    int y0=max(y-r,0), y1=min(y+r,H_-1), x0=max(x-r,0), x1=min(x+r,W_-1);
    bool covered = (y0==0)&&(y1==H_-1)&&(x0==0)&&(x1==W_-1);
#pragma unroll
    for (int q=0;q<9;++q) arr[q] = ~0ull;
    for (int yy=y0; yy<=y1; ++yy){
      int rowb = yy*W_;
      int s = cellst[rowb + x0];
      int e = cellst[rowb + x1 + 1];
      for (int p=s; p<e; ++p){
        unsigned u = psort[p];
        int py = (int)(u>>24), px = (int)((u>>14)&1023), pi = (int)(u&16383);
        int dy = y-py, dx = x-px;
        int d2 = dy*dy + dx*dx;
        ull key = ((ull)(unsigned)d2 << 14) | (unsigned)pi;
        if (key < arr[8]){
          int q = 8;
          while (q > 0 && arr[q-1] > key){ arr[q] = arr[q-1]; --q; }
          arr[q] = key;
        }
      }
    }
    if (covered) break;
    if (arr[8] != ~0ull){
      int d9 = (int)(arr[8] >> 14);
      if (d9 < (r+1)*(r+1)) break;
    }
    r <<= 1;
  }
  const float* gath = ws + HDR_ + 2*NC_;
  float acc[16];
#pragma unroll
  for (int c=0;c<16;++c) acc[c] = 0.f;
  for (int nb=1; nb<9; ++nb){
    int idx = (int)(arr[nb] & 16383ull);
    const float4* s4 = (const float4*)(gath + idx*16);
#pragma unroll
    for (int rq=0; rq<4; ++rq){
      float4 v = s4[rq];
      acc[rq*4]+=v.x; acc[rq*4+1]+=v.y; acc[rq*4+2]+=v.z; acc[rq*4+3]+=v.w;
    }
  }
  float* neigh = ws + HDR_ + 7*NC_;
  float o[16];
#pragma unroll
  for (int c=0;c<16;++c) o[c] = acc[c]*0.125f;
  STORE16(neigh + i*16, o);
}

__global__ __launch_bounds__(64) void k_lin1(
    const float* __restrict__ pf, const int* __restrict__ grid,
    const float* __restrict__ Wk, const float* __restrict__ bk,
    const float* __restrict__ Wfc, const float* __restrict__ bfc,
    float* __restrict__ ws)
{
  __shared__ float sWk[256], sbk[16], sWfc[32], sbfc[16];
  int t = threadIdx.x;
  for (int j=t;j<256;j+=64) sWk[j] = Wk[j];
  if (t < 16){ sbk[t]=bk[t]; sbfc[t]=bfc[t]; }
  if (t < 32) sWfc[t] = Wfc[t];
  __syncthreads();
  int i = blockIdx.x*64 + t;
  float p[16]; LOAD16(p, pf + i*16);
  float ok[16];
#pragma unroll
  for (int c=0;c<16;++c) ok[c] = sbk[c];
#pragma unroll
  for (int j=0;j<16;++j){ float v = p[j];
#pragma unroll
    for (int c=0;c<16;++c) ok[c] += v*sWk[j*16+c];
  }
  float* pts_lin = ws + HDR_;
  STORE16(pts_lin + i*16, ok);
  float cy=ws[264], cx=ws[265], imy=ws[266], imx=ws[267];
  int2 g = ((const int2*)grid)[i];
  float ry = ((float)g.x - cy)*imy, rx = ((float)g.y - cx)*imx;
  float op[16];
#pragma unroll
  for (int c=0;c<16;++c) op[c] = ry*sWfc[c] + rx*sWfc[16+c] + sbfc[c];
  float* pos_lin = ws + HDR_ + NC_;
  STORE16(pos_lin + i*16, op);
#pragma unroll
  for (int c=0;c<16;++c){
    float a = wsum64(ok[c]); float b = wsum64(ok[c]*ok[c]);
    if (t==0){ atomicAdd(&ws[8+c], a); atomicAdd(&ws[24+c], b); }
    a = wsum64(op[c]); b = wsum64(op[c]*op[c]);
    if (t==0){ atomicAdd(&ws[40+c], a); atomicAdd(&ws[56+c], b); }
  }
}

__global__ void k_bnfin(const float* __restrict__ g, const float* __restrict__ b,
                        float* __restrict__ ws, int sumOff, int aOff)
{
  int c = threadIdx.x;
  if (c >= 16) return;
  float mu  = ws[sumOff+c]   * (1.f/N_);
  float var = ws[sumOff+16+c]* (1.f/N_) - mu*mu;
  float a = g[c] / sqrtf(var + EPS_);
  ws[aOff+c]    = a;
  ws[aOff+16+c] = b[c] - mu*a;
}

__global__ __launch_bounds__(64) void k_qstage(
    const float* __restrict__ Wt, const float* __restrict__ bt,
    const float* __restrict__ Woff, const float* __restrict__ boff,
    const float* __restrict__ Wattn, const float* __restrict__ battn,
    float* __restrict__ ws)
{
  __shared__ float sWt[256], sWoff[512], sWattn[256];
  __shared__ float sbt[16], sboff[32], sbattn[16];
  __shared__ float skA[16], skC[16], sfcA[16], sfcC[16];
  int t = threadIdx.x;
  for (int j=t;j<256;j+=64){ sWt[j]=Wt[j]; sWattn[j]=Wattn[j]; }
  for (int j=t;j<512;j+=64) sWoff[j]=Woff[j];
  if (t<16){ sbt[t]=bt[t]; sbattn[t]=battn[t];
    skA[t]=ws[136+t]; skC[t]=ws[152+t]; sfcA[t]=ws[168+t]; sfcC[t]=ws[184+t]; }
  if (t<32) sboff[t]=boff[t];
  __syncthreads();
  int i = blockIdx.x*64 + t;
  float* pts_lin = ws + HDR_;
  float* pos_lin = ws + HDR_ + NC_;
  float* t_lin   = ws + HDR_ + 3*NC_;
  float* offp    = ws + HDR_ + 4*NC_;
  float* attnp   = ws + HDR_ + 6*NC_;
  float pl[16], po[16];
  LOAD16(pl, pts_lin + i*16);
  LOAD16(po, pos_lin + i*16);
  float pts[16], q[16];
#pragma unroll
  for (int c=0;c<16;++c){ pts[c] = pl[c]*skA[c]+skC[c]; q[c] = pts[c] + po[c]*sfcA[c]+sfcC[c]; }
  float tv[16];
#pragma unroll
  for (int c=0;c<16;++c) tv[c] = sbt[c];
#pragma unroll
  for (int j=0;j<16;++j){ float v=pts[j];
#pragma unroll
    for (int c=0;c<16;++c) tv[c] += v*sWt[j*16+c];
  }
  STORE16(t_lin + i*16, tv);
#pragma unroll
  for (int c=0;c<16;++c){
    float a = wsum64(tv[c]); float b = wsum64(tv[c]*tv[c]);
    if (t==0){ atomicAdd(&ws[72+c], a); atomicAdd(&ws[88+c], b); }
  }
  float ov[32];
#pragma unroll
  for (int o=0;o<32;++o) ov[o] = sboff[o];
#pragma unroll
  for (int j=0;j<16;++j){ float v=q[j];
#pragma unroll
    for (int o=0;o<32;++o) ov[o] += v*sWoff[j*32+o];
  }
  { float4* d=(float4*)(offp + i*32);
#pragma unroll
    for (int r=0;r<8;++r) d[r]=make_float4(ov[r*4],ov[r*4+1],ov[r*4+2],ov[r*4+3]);
  }
  float l[16];
#pragma unroll
  for (int c=0;c<16;++c) l[c] = sbattn[c];
#pragma unroll
  for (int j=0;j<16;++j){ float v=q[j];
#pragma unroll
    for (int c=0;c<16;++c) l[c] += v*sWattn[j*16+c];
  }
  float av[16];
#pragma unroll
  for (int h=0;h<4;++h){
    float m = fmaxf(fmaxf(l[h*4],l[h*4+1]),fmaxf(l[h*4+2],l[h*4+3]));
    float e0=expf(l[h*4]-m), e1=expf(l[h*4+1]-m), e2=expf(l[h*4+2]-m), e3=expf(l[h*4+3]-m);
    float inv = 1.f/(e0+e1+e2+e3);
    av[h*4]=e0*inv; av[h*4+1]=e1*inv; av[h*4+2]=e2*inv; av[h*4+3]=e3*inv;
  }
  STORE16(attnp + i*16, av);
}

__global__ __launch_bounds__(256) void k_val(const float* __restrict__ imf,
    const float* __restrict__ Wval, const float* __restrict__ bval, float* __restrict__ ws)
{
  __shared__ float sW[256], sb[16];
  int t = threadIdx.x;
  sW[t] = Wval[t];
  if (t < 16) sb[t] = bval[t];
  __syncthreads();
  int pix = blockIdx.x*256 + t;
  float a[16];
#pragma unroll
  for (int ci=0;ci<16;++ci) a[ci] = imf[ci*HW_ + pix];
  float o[16];
#pragma unroll
  for (int c=0;c<16;++c) o[c] = sb[c];
#pragma unroll
  for (int ci=0;ci<16;++ci){ float v=a[ci];
#pragma unroll
    for (int c=0;c<16;++c) o[c] += v*sW[ci*16+c];
  }
  float* val = ws + VAL_;
  STORE16(val + pix*16, o);
}

// deformable attn + Wout + fuse matmul; (point, head) parallelism, 64 pts/block
__global__ __launch_bounds__(256) void k_attn(
    const int* __restrict__ grid,
    const float* __restrict__ Wout, const float* __restrict__ bout,
    const float* __restrict__ Wf, const float* __restrict__ bf,
    float* __restrict__ ws)
{
  __shared__ float sWout[256], sWf[512], sbout[16], sbf[16], stA[16], stC[16];
  __shared__ float sTl[1024], sNei[1024], sSamp[1024], sImg[1024];
  int t = threadIdx.x;
  int p = t >> 2, h = t & 3;
  int i = blockIdx.x*64 + p;
  sWout[t]=Wout[t]; sWf[t]=Wf[t]; sWf[t+256]=Wf[t+256];
  if (t<16){ sbout[t]=bout[t]; sbf[t]=bf[t]; stA[t]=ws[200+t]; stC[t]=ws[216+t]; }
  // stage t_lin (BN+relu applied) and neigh for this block's 64 points
  {
    const float4* tl4 = (const float4*)(ws + HDR_ + 3*NC_ + blockIdx.x*1024);
    const float4* nv4 = (const float4*)(ws + HDR_ + 7*NC_ + blockIdx.x*1024);
    float4 v = tl4[t];
    int c0 = (t*4) & 15;
    // need stA/stC: written by threads t<16 above, same wave ordering not guaranteed across waves
    // -> recompute locally from ws (cheap, avoids an extra barrier)
    float a0=ws[200+c0],a1=ws[200+c0+1],a2=ws[200+c0+2],a3=ws[200+c0+3];
    float c0v=ws[216+c0],c1v=ws[216+c0+1],c2v=ws[216+c0+2],c3v=ws[216+c0+3];
    sTl[t*4]   = fmaxf(v.x*a0+c0v, 0.f);
    sTl[t*4+1] = fmaxf(v.y*a1+c1v, 0.f);
    sTl[t*4+2] = fmaxf(v.z*a2+c2v, 0.f);
    sTl[t*4+3] = fmaxf(v.w*a3+c3v, 0.f);
    float4 nv = nv4[t];
    sNei[t*4]=nv.x; sNei[t*4+1]=nv.y; sNei[t*4+2]=nv.z; sNei[t*4+3]=nv.w;
  }
  // per (p,h): offsets (8 floats), attn weights (4), grid pos
  const float4* off4 = (const float4*)(ws + HDR_ + 4*NC_ + blockIdx.x*2048);
  float4 o0 = off4[t*2], o1 = off4[t*2+1];
  float4 aw = ((const float4*)(ws + HDR_ + 6*NC_ + blockIdx.x*1024))[t];
  int2 g = ((const int2*)grid)[i];
  float y = (float)g.x, x = (float)g.y;
  const float4* val4 = (const float4*)(ws + VAL_);
  float4 acc = make_float4(0.f,0.f,0.f,0.f);
  float offv[8] = {o0.x,o0.y,o0.z,o0.w,o1.x,o1.y,o1.z,o1.w};
  float avv[4]  = {aw.x,aw.y,aw.z,aw.w};
#define CORNER(yy,xx,wgt) do{ int _y=(yy),_x=(xx); \
    if ((unsigned)_y < (unsigned)H_ && (unsigned)_x < (unsigned)W_){ \
      float4 _v = val4[(_y*W_+_x)*4 + h]; float _w = a*(wgt); \
      acc.x += _w*_v.x; acc.y += _w*_v.y; acc.z += _w*_v.z; acc.w += _w*_v.w; } }while(0)
#pragma unroll
  for (int pt=0; pt<4; ++pt){
    float a  = avv[pt];
    float ly = y + offv[pt*2], lx = x + offv[pt*2+1];
    float fy = floorf(ly), fx = floorf(lx);
    float wy = ly - fy, wx = lx - fx;
    int y0 = (int)fy, x0 = (int)fx;
    CORNER(y0,   x0,   (1.f-wy)*(1.f-wx));
    CORNER(y0,   x0+1, (1.f-wy)*wx);
    CORNER(y0+1, x0,   wy*(1.f-wx));
    CORNER(y0+1, x0+1, wy*wx);
  }
#undef CORNER
  ((float4*)sSamp)[t] = acc;   // sSamp[p*16 + h*4 ..]
  __syncthreads();
  // img channels cc = h*4..h*4+3 for point p
  float img[4];
#pragma unroll
  for (int k=0;k<4;++k){ int cc=h*4+k; img[k] = sbout[cc] + sNei[p*16+cc]; }
#pragma unroll
  for (int j=0;j<16;++j){
    float v = sSamp[p*16+j];
#pragma unroll
    for (int k=0;k<4;++k) img[k] += v*sWout[j*16 + h*4 + k];
  }
  ((float4*)sImg)[t] = make_float4(img[0],img[1],img[2],img[3]);
  __syncthreads();
  // f_lin channels cc for point p
  float fl[4];
#pragma unroll
  for (int k=0;k<4;++k) fl[k] = sbf[h*4+k];
#pragma unroll
  for (int j=0;j<16;++j){
    float v1 = sTl[p*16+j];
    float v2 = fmaxf(sImg[p*16+j], 0.f);
#pragma unroll
    for (int k=0;k<4;++k){
      fl[k] += v1*sWf[j*16 + h*4 + k];
      fl[k] += v2*sWf[(16+j)*16 + h*4 + k];
    }
  }
  float* f_lin = ws + HDR_ + 8*NC_;
  ((float4*)(f_lin + blockIdx.x*1024))[t] = make_float4(fl[0],fl[1],fl[2],fl[3]);
}

__global__ __launch_bounds__(64) void k_statsF(float* __restrict__ ws){
  int t = threadIdx.x;
  int i = blockIdx.x*64 + t;
  float fl[16]; LOAD16(fl, ws + HDR_ + 8*NC_ + i*16);
#pragma unroll
  for (int c=0;c<16;++c){
    float a = wsum64(fl[c]); float b = wsum64(fl[c]*fl[c]);
    if (t==0){ atomicAdd(&ws[104+c], a); atomicAdd(&ws[120+c], b); }
  }
}

__global__ __launch_bounds__(256) void k_out(const float* __restrict__ ws, float* __restrict__ out){
  int idx = blockIdx.x*256 + threadIdx.x;
  int c = idx & 15;
  float v = ws[HDR_ + 8*NC_ + idx];
  out[idx] = fmaxf(v*ws[232+c] + ws[248+c], 0.f);
}

extern "C" void kernel_launch(void* const* d_in, const int* in_sizes, int n_in,
                              void* d_out, int out_size, void* d_ws, size_t ws_size,
                              hipStream_t stream)
{
  const float* pf    = (const float*)d_in[0];
  const float* imf   = (const float*)d_in[1];
  const int*   gridp = (const int*)d_in[2];
  const float* Wk   =(const float*)d_in[3],  *bk   =(const float*)d_in[4];
  const float* gk   =(const float*)d_in[5],  *betak=(const float*)d_in[6];
  const float* Wfc  =(const float*)d_in[7],  *bfc  =(const float*)d_in[8];
  const float* gfc  =(const float*)d_in[9],  *betafc=(const float*)d_in[10];
  const float* Wt   =(const float*)d_in[11], *bt   =(const float*)d_in[12];
  const float* gt   =(const float*)d_in[13], *betat=(const float*)d_in[14];
  const float* Woff =(const float*)d_in[15], *boff =(const float*)d_in[16];
  const float* Wattn=(const float*)d_in[17], *battn=(const float*)d_in[18];
  const float* Wval =(const float*)d_in[19], *bval =(const float*)d_in[20];
  const float* Wout =(const float*)d_in[21], *bout =(const float*)d_in[22];
  const float* Wf   =(const float*)d_in[23], *bf   =(const float*)d_in[24];
  const float* gf   =(const float*)d_in[25], *betaf=(const float*)d_in[26];
  float* ws  = (float*)d_ws;
  float* out = (float*)d_out;

  hipLaunchKernelGGL(k_init,      dim3(1),        dim3(128), 0, stream, ws);
  hipLaunchKernelGGL(k_gridstats, dim3(N_/256),   dim3(256), 0, stream, gridp, ws);
  hipLaunchKernelGGL(k_gridfin,   dim3(1),        dim3(1),   0, stream, ws);
  hipLaunchKernelGGL(k_zero,      dim3(176),      dim3(256), 0, stream, ws);
  hipLaunchKernelGGL(k_count,     dim3(N_/256),   dim3(256), 0, stream, gridp, ws);
  hipLaunchKernelGGL(k_scanA,     dim3(704),      dim3(256), 0, stream, ws);
  hipLaunchKernelGGL(k_scanB,     dim3(1),        dim3(256), 0, stream, ws);
  hipLaunchKernelGGL(k_scanC,     dim3(704),      dim3(256), 0, stream, ws);
  hipLaunchKernelGGL(k_scatter,   dim3(N_/256),   dim3(256), 0, stream, gridp, ws);
  hipLaunchKernelGGL(k_gath,      dim3(NC_/256),  dim3(256), 0, stream, imf, gridp, ws);
  hipLaunchKernelGGL(k_lin1,      dim3(N_/64),    dim3(64),  0, stream, pf, gridp, Wk, bk, Wfc, bfc, ws);
  hipLaunchKernelGGL(k_bnfin,     dim3(1),        dim3(16),  0, stream, gk, betak, ws, 8, 136);
  hipLaunchKernelGGL(k_bnfin,     dim3(1),        dim3(16),  0, stream, gfc, betafc, ws, 40, 168);
  hipLaunchKernelGGL(k_qstage,    dim3(N_/64),    dim3(64),  0, stream, Wt, bt, Woff, boff, Wattn, battn, ws);
  hipLaunchKernelGGL(k_bnfin,     dim3(1),        dim3(16),  0, stream, gt, betat, ws, 72, 200);
  hipLaunchKernelGGL(k_val,       dim3(HW_/256),  dim3(256), 0, stream, imf, Wval, bval, ws);
  hipLaunchKernelGGL(k_knn2,      dim3(N_/64),    dim3(64),  0, stream, ws);
  hipLaunchKernelGGL(k_attn,      dim3(N_/64),    dim3(256), 0, stream, gridp, Wout, bout, Wf, bf, ws);
  hipLaunchKernelGGL(k_statsF,    dim3(N_/64),    dim3(64),  0, stream, ws);
  hipLaunchKernelGGL(k_bnfin,     dim3(1),        dim3(16),  0, stream, gf, betaf, ws, 104, 232);
  hipLaunchKernelGGL(k_out,       dim3(NC_/256),  dim3(256), 0, stream, ws, out);
}

// Round 4
// 274.960 us; speedup vs baseline: 4.4823x; 1.7226x over previous
//
#include <hip/hip_runtime.h>
#include <climits>

#define N_ 16384
#define C_ 16
#define H_ 256
#define W_ 704
#define HW_ (H_*W_)
#define NC_ (N_*C_)
#define EPS_ 1e-3f
#define HDR_ 512

typedef unsigned long long ull;

// ---- workspace layout (float units) ----
// ints [0..5]: sum_y, sum_x, min_y, max_y, min_x, max_x
// [136..151] kA  [152..167] kC   [168..183] fcA [184..199] fcC
// [200..215] tA  [216..231] tC   [232..247] fA  [248..263] fC
// [264] cy [265] cx [266] inv_mx_y [267] inv_mx_x
// arrays at HDR_: pts_lin(0) pos_lin(1) gath(2) t_lin(3) off(4,5) attn(6) neigh(7) f_lin(8) val(9..)
// KNN int scratch after val: counts(180224) cellstart(180240) bsum(704) boff(704) psort(16384)
// partials: partK/partFC/partT live in the (not-yet-written) val region; partF after psort.

#define VAL_  (HDR_ + 9*NC_)
#define KNNI_ (VAL_ + HW_*16)
#define PARTF_ (KNNI_ + 378256)

__device__ __forceinline__ float wsum64(float v){
#pragma unroll
  for (int o = 32; o > 0; o >>= 1) v += __shfl_down(v, o);
  return v;
}

#define LOAD16(dst, src) { const float4* _s=(const float4*)(src); float4 _a=_s[0],_b=_s[1],_c=_s[2],_d=_s[3]; \
  dst[0]=_a.x;dst[1]=_a.y;dst[2]=_a.z;dst[3]=_a.w; dst[4]=_b.x;dst[5]=_b.y;dst[6]=_b.z;dst[7]=_b.w; \
  dst[8]=_c.x;dst[9]=_c.y;dst[10]=_c.z;dst[11]=_c.w; dst[12]=_d.x;dst[13]=_d.y;dst[14]=_d.z;dst[15]=_d.w; }

#define STORE16(dst, src) { float4* _d=(float4*)(dst); \
  _d[0]=make_float4(src[0],src[1],src[2],src[3]); _d[1]=make_float4(src[4],src[5],src[6],src[7]); \
  _d[2]=make_float4(src[8],src[9],src[10],src[11]); _d[3]=make_float4(src[12],src[13],src[14],src[15]); }

// zero cell counts + init header ints
__global__ __launch_bounds__(256) void k_init(float* ws){
  if (blockIdx.x < 176){
    int4* c = (int4*)(ws + KNNI_);
    c[blockIdx.x*256 + threadIdx.x] = make_int4(0,0,0,0);
  } else if (threadIdx.x == 0){
    int* ih = (int*)ws;
    ih[0]=0; ih[1]=0; ih[2]=INT_MAX; ih[3]=INT_MIN; ih[4]=INT_MAX; ih[5]=INT_MIN;
  }
}

// grid stats (block-level pre-reduction -> 6 atomics/block) + cell count
__global__ __launch_bounds__(256) void k_gridcnt(const int* __restrict__ grid, float* __restrict__ ws){
  int i = blockIdx.x*256 + threadIdx.x;
  int2 p = ((const int2*)grid)[i];
  int* counts = (int*)(ws + KNNI_);
  atomicAdd(&counts[p.x*W_ + p.y], 1);
  int sy=p.x, sx=p.y, mny=p.x, mxy=p.x, mnx=p.y, mxx=p.y;
#pragma unroll
  for (int o=32;o>0;o>>=1){
    sy += __shfl_down(sy,o); sx += __shfl_down(sx,o);
    mny = min(mny,__shfl_down(mny,o)); mxy = max(mxy,__shfl_down(mxy,o));
    mnx = min(mnx,__shfl_down(mnx,o)); mxx = max(mxx,__shfl_down(mxx,o));
  }
  __shared__ int sh[24];
  int w = threadIdx.x >> 6;
  if ((threadIdx.x & 63) == 0){
    sh[w]=sy; sh[4+w]=sx; sh[8+w]=mny; sh[12+w]=mxy; sh[16+w]=mnx; sh[20+w]=mxx;
  }
  __syncthreads();
  if (threadIdx.x == 0){
    int a0=sh[0]+sh[1]+sh[2]+sh[3];
    int a1=sh[4]+sh[5]+sh[6]+sh[7];
    int a2=min(min(sh[8],sh[9]),min(sh[10],sh[11]));
    int a3=max(max(sh[12],sh[13]),max(sh[14],sh[15]));
    int a4=min(min(sh[16],sh[17]),min(sh[18],sh[19]));
    int a5=max(max(sh[20],sh[21]),max(sh[22],sh[23]));
    int* ih = (int*)ws;
    atomicAdd(&ih[0],a0); atomicAdd(&ih[1],a1);
    atomicMin(&ih[2],a2); atomicMax(&ih[3],a3);
    atomicMin(&ih[4],a4); atomicMax(&ih[5],a5);
  }
}

__global__ __launch_bounds__(256) void k_scanA(float* ws){
  const int* counts = (const int*)(ws + KNNI_);
  int* bsum = (int*)(ws + KNNI_) + 180224 + 180240;
  int t = threadIdx.x;
  int v = counts[blockIdx.x*256 + t];
#pragma unroll
  for (int o=32;o>0;o>>=1) v += __shfl_down(v,o);
  __shared__ int w4[4];
  if ((t&63)==0) w4[t>>6] = v;
  __syncthreads();
  if (t==0) bsum[blockIdx.x] = w4[0]+w4[1]+w4[2]+w4[3];
}

// block-sum exclusive scan (+ grid center/scale finalize)
__global__ __launch_bounds__(256) void k_scanB(float* ws){
  if (threadIdx.x == 0){
    int* ih = (int*)ws;
    float cy = (float)ih[0] / (float)N_;
    float cx = (float)ih[1] / (float)N_;
    float my = fmaxf((float)ih[3]-cy, cy-(float)ih[2]);
    float mx = fmaxf((float)ih[5]-cx, cx-(float)ih[4]);
    if (my == 0.f) my = 1.f;
    if (mx == 0.f) mx = 1.f;
    ws[264]=cy; ws[265]=cx; ws[266]=1.f/my; ws[267]=1.f/mx;
  }
  int* bsum = (int*)(ws + KNNI_) + 180224 + 180240;
  int* boff = bsum + 704;
  __shared__ int tmp[256];
  __shared__ int carry;
  int t = threadIdx.x;
  if (t==0) carry = 0;
  __syncthreads();
  for (int c=0;c<3;++c){
    int idx = c*256 + t;
    int v = (idx < 704) ? bsum[idx] : 0;
    tmp[t] = v;
    __syncthreads();
    for (int o=1;o<256;o<<=1){
      int x = (t>=o) ? tmp[t-o] : 0;
      __syncthreads();
      tmp[t] += x;
      __syncthreads();
    }
    int incl = tmp[t];
    int base = carry;
    if (idx < 704) boff[idx] = base + incl - v;
    __syncthreads();
    if (t==255) carry = base + incl;
    __syncthreads();
  }
}

__global__ __launch_bounds__(256) void k_scanC(float* ws){
  int* counts = (int*)(ws + KNNI_);
  int* cellst = counts + 180224;
  const int* boff = counts + 180224 + 180240 + 704;
  __shared__ int tmp[256];
  int t = threadIdx.x;
  int i = blockIdx.x*256 + t;
  int v = counts[i];
  tmp[t] = v;
  __syncthreads();
  for (int o=1;o<256;o<<=1){
    int x = (t>=o) ? tmp[t-o] : 0;
    __syncthreads();
    tmp[t] += x;
    __syncthreads();
  }
  int start = boff[blockIdx.x] + tmp[t] - v;
  cellst[i] = start;
  counts[i] = start;          // becomes the scatter cursor
  if (i == 0) cellst[HW_] = N_;
}

__global__ __launch_bounds__(256) void k_scatter(const int* __restrict__ grid, float* __restrict__ ws){
  int i = blockIdx.x*256 + threadIdx.x;
  int2 g = ((const int2*)grid)[i];
  int* counts = (int*)(ws + KNNI_);
  unsigned* psort = (unsigned*)(counts + 180224 + 180240 + 704 + 704);
  int pos = atomicAdd(&counts[g.x*W_ + g.y], 1);
  psort[pos] = ((unsigned)g.x<<24) | ((unsigned)g.y<<14) | (unsigned)i;
}

// wide gather: one thread per (point, channel)
__global__ __launch_bounds__(256) void k_gath(const float* __restrict__ imf,
                                              const int* __restrict__ grid,
                                              float* __restrict__ ws){
  int idx = blockIdx.x*256 + threadIdx.x;   // 0..262143
  int i = idx >> 4, c = idx & 15;
  int2 g = ((const int2*)grid)[i];
  ws[HDR_ + 2*NC_ + idx] = imf[c*HW_ + g.x*W_ + g.y];
}

// exact KNN (points processed in cell-sorted order for wave coherence)
__global__ __launch_bounds__(64) void k_knn2(float* __restrict__ ws){
  int gid = blockIdx.x*64 + threadIdx.x;
  const int* cellst = (const int*)(ws + KNNI_) + 180224;
  const unsigned* psort = (const unsigned*)((const int*)(ws + KNNI_) + 180224 + 180240 + 704 + 704);
  unsigned me = psort[gid];
  int y = (int)(me>>24), x = (int)((me>>14)&1023), i = (int)(me&16383);
  int r = 8;
  for (;;){
    int y0=max(y-r,0), y1=min(y+r,H_-1), x0=max(x-r,0), x1=min(x+r,W_-1);
    bool covered = (y0==0)&&(y1==H_-1)&&(x0==0)&&(x1==W_-1);
    int area = (y1-y0+1)*(x1-x0+1);
    if (area >= 224 || covered) break;
    r += 8;
  }
  ull arr[9];
  for (;;){
    int y0=max(y-r,0), y1=min(y+r,H_-1), x0=max(x-r,0), x1=min(x+r,W_-1);
    bool covered = (y0==0)&&(y1==H_-1)&&(x0==0)&&(x1==W_-1);
#pragma unroll
    for (int q=0;q<9;++q) arr[q] = ~0ull;
    for (int yy=y0; yy<=y1; ++yy){
      int rowb = yy*W_;
      int s = cellst[rowb + x0];
      int e = cellst[rowb + x1 + 1];
      for (int p=s; p<e; ++p){
        unsigned u = psort[p];
        int py = (int)(u>>24), px = (int)((u>>14)&1023), pi = (int)(u&16383);
        int dy = y-py, dx = x-px;
        int d2 = dy*dy + dx*dx;
        ull key = ((ull)(unsigned)d2 << 14) | (unsigned)pi;
        if (key < arr[8]){
          int q = 8;
          while (q > 0 && arr[q-1] > key){ arr[q] = arr[q-1]; --q; }
          arr[q] = key;
        }
      }
    }
    if (covered) break;
    if (arr[8] != ~0ull){
      int d9 = (int)(arr[8] >> 14);
      if (d9 < (r+1)*(r+1)) break;
    }
    r <<= 1;
  }
  const float* gath = ws + HDR_ + 2*NC_;
  float acc[16];
#pragma unroll
  for (int c=0;c<16;++c) acc[c] = 0.f;
  for (int nb=1; nb<9; ++nb){
    int idx = (int)(arr[nb] & 16383ull);
    const float4* s4 = (const float4*)(gath + idx*16);
#pragma unroll
    for (int rq=0; rq<4; ++rq){
      float4 v = s4[rq];
      acc[rq*4]+=v.x; acc[rq*4+1]+=v.y; acc[rq*4+2]+=v.z; acc[rq*4+3]+=v.w;
    }
  }
  float* neigh = ws + HDR_ + 7*NC_;
  float o[16];
#pragma unroll
  for (int c=0;c<16;++c) o[c] = acc[c]*0.125f;
  STORE16(neigh + i*16, o);
}

__global__ __launch_bounds__(64) void k_lin1(
    const float* __restrict__ pf, const int* __restrict__ grid,
    const float* __restrict__ Wk, const float* __restrict__ bk,
    const float* __restrict__ Wfc, const float* __restrict__ bfc,
    float* __restrict__ ws)
{
  __shared__ float sWk[256], sbk[16], sWfc[32], sbfc[16];
  int t = threadIdx.x;
  for (int j=t;j<256;j+=64) sWk[j] = Wk[j];
  if (t < 16){ sbk[t]=bk[t]; sbfc[t]=bfc[t]; }
  if (t < 32) sWfc[t] = Wfc[t];
  __syncthreads();
  int i = blockIdx.x*64 + t;
  float p[16]; LOAD16(p, pf + i*16);
  float ok[16];
#pragma unroll
  for (int c=0;c<16;++c) ok[c] = sbk[c];
#pragma unroll
  for (int j=0;j<16;++j){ float v = p[j];
#pragma unroll
    for (int c=0;c<16;++c) ok[c] += v*sWk[j*16+c];
  }
  float* pts_lin = ws + HDR_;
  STORE16(pts_lin + i*16, ok);
  float cy=ws[264], cx=ws[265], imy=ws[266], imx=ws[267];
  int2 g = ((const int2*)grid)[i];
  float ry = ((float)g.x - cy)*imy, rx = ((float)g.y - cx)*imx;
  float op[16];
#pragma unroll
  for (int c=0;c<16;++c) op[c] = ry*sWfc[c] + rx*sWfc[16+c] + sbfc[c];
  float* pos_lin = ws + HDR_ + NC_;
  STORE16(pos_lin + i*16, op);
  // contention-free partial stats
  float* partK  = ws + VAL_;
  float* partFC = ws + VAL_ + 8192;
#pragma unroll
  for (int c=0;c<16;++c){
    float a = wsum64(ok[c]); float b = wsum64(ok[c]*ok[c]);
    if (t==0){ partK[blockIdx.x*32+c]=a; partK[blockIdx.x*32+16+c]=b; }
    a = wsum64(op[c]); b = wsum64(op[c]*op[c]);
    if (t==0){ partFC[blockIdx.x*32+c]=a; partFC[blockIdx.x*32+16+c]=b; }
  }
}

// reduce 256x32 partials -> BN affine coefs (fuses bnfin)
__device__ __forceinline__ void red1_body(const float* __restrict__ g, const float* __restrict__ b,
                                          float* __restrict__ ws, int partOff, int aOff, float* red){
  int t = threadIdx.x, slot = t & 31, chunk = t >> 5;
  const float* part = ws + partOff;
  float acc = 0.f;
  for (int bb=chunk*32; bb<chunk*32+32; ++bb) acc += part[bb*32 + slot];
  red[t] = acc;
  __syncthreads();
  if (chunk == 0){
    float v = red[slot];
#pragma unroll
    for (int k2=1;k2<8;++k2) v += red[k2*32+slot];
    red[slot] = v;
  }
  __syncthreads();
  if (t < 16){
    float mu  = red[t]    * (1.f/N_);
    float var = red[16+t] * (1.f/N_) - mu*mu;
    float a = g[t] / sqrtf(var + EPS_);
    ws[aOff+t]    = a;
    ws[aOff+16+t] = b[t] - mu*a;
  }
  __syncthreads();
}

__global__ __launch_bounds__(256) void k_red2(const float* __restrict__ gk, const float* __restrict__ betak,
                                              const float* __restrict__ gfc, const float* __restrict__ betafc,
                                              float* __restrict__ ws){
  __shared__ float red[256];
  red1_body(gk, betak, ws, VAL_, 136, red);
  red1_body(gfc, betafc, ws, VAL_+8192, 168, red);
}

__global__ __launch_bounds__(256) void k_red1(const float* __restrict__ g, const float* __restrict__ b,
                                              float* __restrict__ ws, int partOff, int aOff){
  __shared__ float red[256];
  red1_body(g, b, ws, partOff, aOff, red);
}

__global__ __launch_bounds__(64) void k_qstage(
    const float* __restrict__ Wt, const float* __restrict__ bt,
    const float* __restrict__ Woff, const float* __restrict__ boff,
    const float* __restrict__ Wattn, const float* __restrict__ battn,
    float* __restrict__ ws)
{
  __shared__ float sWt[256], sWoff[512], sWattn[256];
  __shared__ float sbt[16], sboff[32], sbattn[16];
  __shared__ float skA[16], skC[16], sfcA[16], sfcC[16];
  int t = threadIdx.x;
  for (int j=t;j<256;j+=64){ sWt[j]=Wt[j]; sWattn[j]=Wattn[j]; }
  for (int j=t;j<512;j+=64) sWoff[j]=Woff[j];
  if (t<16){ sbt[t]=bt[t]; sbattn[t]=battn[t];
    skA[t]=ws[136+t]; skC[t]=ws[152+t]; sfcA[t]=ws[168+t]; sfcC[t]=ws[184+t]; }
  if (t<32) sboff[t]=boff[t];
  __syncthreads();
  int i = blockIdx.x*64 + t;
  float* pts_lin = ws + HDR_;
  float* pos_lin = ws + HDR_ + NC_;
  float* t_lin   = ws + HDR_ + 3*NC_;
  float* offp    = ws + HDR_ + 4*NC_;
  float* attnp   = ws + HDR_ + 6*NC_;
  float pl[16], po[16];
  LOAD16(pl, pts_lin + i*16);
  LOAD16(po, pos_lin + i*16);
  float pts[16], q[16];
#pragma unroll
  for (int c=0;c<16;++c){ pts[c] = pl[c]*skA[c]+skC[c]; q[c] = pts[c] + po[c]*sfcA[c]+sfcC[c]; }
  float tv[16];
#pragma unroll
  for (int c=0;c<16;++c) tv[c] = sbt[c];
#pragma unroll
  for (int j=0;j<16;++j){ float v=pts[j];
#pragma unroll
    for (int c=0;c<16;++c) tv[c] += v*sWt[j*16+c];
  }
  STORE16(t_lin + i*16, tv);
  float* partT = ws + VAL_ + 16384;
#pragma unroll
  for (int c=0;c<16;++c){
    float a = wsum64(tv[c]); float b = wsum64(tv[c]*tv[c]);
    if (t==0){ partT[blockIdx.x*32+c]=a; partT[blockIdx.x*32+16+c]=b; }
  }
  float ov[32];
#pragma unroll
  for (int o=0;o<32;++o) ov[o] = sboff[o];
#pragma unroll
  for (int j=0;j<16;++j){ float v=q[j];
#pragma unroll
    for (int o=0;o<32;++o) ov[o] += v*sWoff[j*32+o];
  }
  { float4* d=(float4*)(offp + i*32);
#pragma unroll
    for (int r=0;r<8;++r) d[r]=make_float4(ov[r*4],ov[r*4+1],ov[r*4+2],ov[r*4+3]);
  }
  float l[16];
#pragma unroll
  for (int c=0;c<16;++c) l[c] = sbattn[c];
#pragma unroll
  for (int j=0;j<16;++j){ float v=q[j];
#pragma unroll
    for (int c=0;c<16;++c) l[c] += v*sWattn[j*16+c];
  }
  float av[16];
#pragma unroll
  for (int h=0;h<4;++h){
    float m = fmaxf(fmaxf(l[h*4],l[h*4+1]),fmaxf(l[h*4+2],l[h*4+3]));
    float e0=expf(l[h*4]-m), e1=expf(l[h*4+1]-m), e2=expf(l[h*4+2]-m), e3=expf(l[h*4+3]-m);
    float inv = 1.f/(e0+e1+e2+e3);
    av[h*4]=e0*inv; av[h*4+1]=e1*inv; av[h*4+2]=e2*inv; av[h*4+3]=e3*inv;
  }
  STORE16(attnp + i*16, av);
}

__global__ __launch_bounds__(256) void k_val(const float* __restrict__ imf,
    const float* __restrict__ Wval, const float* __restrict__ bval, float* __restrict__ ws)
{
  __shared__ float sW[256], sb[16];
  int t = threadIdx.x;
  sW[t] = Wval[t];
  if (t < 16) sb[t] = bval[t];
  __syncthreads();
  int pix = blockIdx.x*256 + t;
  float a[16];
#pragma unroll
  for (int ci=0;ci<16;++ci) a[ci] = imf[ci*HW_ + pix];
  float o[16];
#pragma unroll
  for (int c=0;c<16;++c) o[c] = sb[c];
#pragma unroll
  for (int ci=0;ci<16;++ci){ float v=a[ci];
#pragma unroll
    for (int c=0;c<16;++c) o[c] += v*sW[ci*16+c];
  }
  float* val = ws + VAL_;
  STORE16(val + pix*16, o);
}

// deformable attn + Wout + fuse matmul + f-stats; (point, head) parallelism, 64 pts/block
__global__ __launch_bounds__(256) void k_attn(
    const int* __restrict__ grid,
    const float* __restrict__ Wout, const float* __restrict__ bout,
    const float* __restrict__ Wf, const float* __restrict__ bf,
    float* __restrict__ ws)
{
  __shared__ float sWout[256], sWf[512], sbout[16], sbf[16];
  __shared__ float sTl[1024], sNei[1024], sSamp[1024], sImg[1024];
  __shared__ float sPart[128];
  int t = threadIdx.x;
  int p = t >> 2, h = t & 3;
  int i = blockIdx.x*64 + p;
  sWout[t]=Wout[t]; sWf[t]=Wf[t]; sWf[t+256]=Wf[t+256];
  if (t<16){ sbout[t]=bout[t]; sbf[t]=bf[t]; }
  {
    const float4* tl4 = (const float4*)(ws + HDR_ + 3*NC_ + blockIdx.x*1024);
    const float4* nv4 = (const float4*)(ws + HDR_ + 7*NC_ + blockIdx.x*1024);
    float4 v = tl4[t];
    int c0 = (t*4) & 15;
    float a0=ws[200+c0],a1=ws[200+c0+1],a2=ws[200+c0+2],a3=ws[200+c0+3];
    float c0v=ws[216+c0],c1v=ws[216+c0+1],c2v=ws[216+c0+2],c3v=ws[216+c0+3];
    sTl[t*4]   = fmaxf(v.x*a0+c0v, 0.f);
    sTl[t*4+1] = fmaxf(v.y*a1+c1v, 0.f);
    sTl[t*4+2] = fmaxf(v.z*a2+c2v, 0.f);
    sTl[t*4+3] = fmaxf(v.w*a3+c3v, 0.f);
    float4 nv = nv4[t];
    sNei[t*4]=nv.x; sNei[t*4+1]=nv.y; sNei[t*4+2]=nv.z; sNei[t*4+3]=nv.w;
  }
  const float4* off4 = (const float4*)(ws + HDR_ + 4*NC_ + blockIdx.x*2048);
  float4 o0 = off4[t*2], o1 = off4[t*2+1];
  float4 aw = ((const float4*)(ws + HDR_ + 6*NC_ + blockIdx.x*1024))[t];
  int2 g = ((const int2*)grid)[i];
  float y = (float)g.x, x = (float)g.y;
  const float4* val4 = (const float4*)(ws + VAL_);
  float4 acc = make_float4(0.f,0.f,0.f,0.f);
  float offv[8] = {o0.x,o0.y,o0.z,o0.w,o1.x,o1.y,o1.z,o1.w};
  float avv[4]  = {aw.x,aw.y,aw.z,aw.w};
#define CORNER(yy,xx,wgt) do{ int _y=(yy),_x=(xx); \
    if ((unsigned)_y < (unsigned)H_ && (unsigned)_x < (unsigned)W_){ \
      float4 _v = val4[(_y*W_+_x)*4 + h]; float _w = a*(wgt); \
      acc.x += _w*_v.x; acc.y += _w*_v.y; acc.z += _w*_v.z; acc.w += _w*_v.w; } }while(0)
#pragma unroll
  for (int pt=0; pt<4; ++pt){
    float a  = avv[pt];
    float ly = y + offv[pt*2], lx = x + offv[pt*2+1];
    float fy = floorf(ly), fx = floorf(lx);
    float wy = ly - fy, wx = lx - fx;
    int y0 = (int)fy, x0 = (int)fx;
    CORNER(y0,   x0,   (1.f-wy)*(1.f-wx));
    CORNER(y0,   x0+1, (1.f-wy)*wx);
    CORNER(y0+1, x0,   wy*(1.f-wx));
    CORNER(y0+1, x0+1, wy*wx);
  }
#undef CORNER
  ((float4*)sSamp)[t] = acc;
  __syncthreads();
  float img[4];
#pragma unroll
  for (int k=0;k<4;++k){ int cc=h*4+k; img[k] = sbout[cc] + sNei[p*16+cc]; }
#pragma unroll
  for (int j=0;j<16;++j){
    float v = sSamp[p*16+j];
#pragma unroll
    for (int k=0;k<4;++k) img[k] += v*sWout[j*16 + h*4 + k];
  }
  ((float4*)sImg)[t] = make_float4(img[0],img[1],img[2],img[3]);
  __syncthreads();
  float fl[4];
#pragma unroll
  for (int k=0;k<4;++k) fl[k] = sbf[h*4+k];
#pragma unroll
  for (int j=0;j<16;++j){
    float v1 = sTl[p*16+j];
    float v2 = fmaxf(sImg[p*16+j], 0.f);
#pragma unroll
    for (int k=0;k<4;++k){
      fl[k] += v1*sWf[j*16 + h*4 + k];
      fl[k] += v2*sWf[(16+j)*16 + h*4 + k];
    }
  }
  float* f_lin = ws + HDR_ + 8*NC_;
  ((float4*)(f_lin + blockIdx.x*1024))[t] = make_float4(fl[0],fl[1],fl[2],fl[3]);
  // f-stats: same-h lanes are stride-4 within a wave; reduce 16 points/wave, then LDS
  float s0=fl[0],s1=fl[1],s2=fl[2],s3=fl[3];
  float q0=fl[0]*fl[0],q1=fl[1]*fl[1],q2=fl[2]*fl[2],q3=fl[3]*fl[3];
#pragma unroll
  for (int o=32;o>=4;o>>=1){
    s0+=__shfl_down(s0,o); s1+=__shfl_down(s1,o); s2+=__shfl_down(s2,o); s3+=__shfl_down(s3,o);
    q0+=__shfl_down(q0,o); q1+=__shfl_down(q1,o); q2+=__shfl_down(q2,o); q3+=__shfl_down(q3,o);
  }
  int wave = t >> 6, lane = t & 63;
  if (lane < 4){
    sPart[wave*32 + lane*4+0]=s0; sPart[wave*32 + lane*4+1]=s1;
    sPart[wave*32 + lane*4+2]=s2; sPart[wave*32 + lane*4+3]=s3;
    sPart[wave*32 + 16 + lane*4+0]=q0; sPart[wave*32 + 16 + lane*4+1]=q1;
    sPart[wave*32 + 16 + lane*4+2]=q2; sPart[wave*32 + 16 + lane*4+3]=q3;
  }
  __syncthreads();
  if (t < 32){
    float v = sPart[t]+sPart[32+t]+sPart[64+t]+sPart[96+t];
    (ws + PARTF_)[blockIdx.x*32 + t] = v;
  }
}

__global__ __launch_bounds__(256) void k_out(const float* __restrict__ ws, float* __restrict__ out){
  int idx = blockIdx.x*256 + threadIdx.x;
  int c = idx & 15;
  float v = ws[HDR_ + 8*NC_ + idx];
  out[idx] = fmaxf(v*ws[232+c] + ws[248+c], 0.f);
}

extern "C" void kernel_launch(void* const* d_in, const int* in_sizes, int n_in,
                              void* d_out, int out_size, void* d_ws, size_t ws_size,
                              hipStream_t stream)
{
  const float* pf    = (const float*)d_in[0];
  const float* imf   = (const float*)d_in[1];
  const int*   gridp = (const int*)d_in[2];
  const float* Wk   =(const float*)d_in[3],  *bk   =(const float*)d_in[4];
  const float* gk   =(const float*)d_in[5],  *betak=(const float*)d_in[6];
  const float* Wfc  =(const float*)d_in[7],  *bfc  =(const float*)d_in[8];
  const float* gfc  =(const float*)d_in[9],  *betafc=(const float*)d_in[10];
  const float* Wt   =(const float*)d_in[11], *bt   =(const float*)d_in[12];
  const float* gt   =(const float*)d_in[13], *betat=(const float*)d_in[14];
  const float* Woff =(const float*)d_in[15], *boff =(const float*)d_in[16];
  const float* Wattn=(const float*)d_in[17], *battn=(const float*)d_in[18];
  const float* Wval =(const float*)d_in[19], *bval =(const float*)d_in[20];
  const float* Wout =(const float*)d_in[21], *bout =(const float*)d_in[22];
  const float* Wf   =(const float*)d_in[23], *bf   =(const float*)d_in[24];
  const float* gf   =(const float*)d_in[25], *betaf=(const float*)d_in[26];
  float* ws  = (float*)d_ws;
  float* out = (float*)d_out;

  hipLaunchKernelGGL(k_init,     dim3(177),     dim3(256), 0, stream, ws);
  hipLaunchKernelGGL(k_gridcnt,  dim3(N_/256),  dim3(256), 0, stream, gridp, ws);
  hipLaunchKernelGGL(k_scanA,    dim3(704),     dim3(256), 0, stream, ws);
  hipLaunchKernelGGL(k_scanB,    dim3(1),       dim3(256), 0, stream, ws);
  hipLaunchKernelGGL(k_scanC,    dim3(704),     dim3(256), 0, stream, ws);
  hipLaunchKernelGGL(k_scatter,  dim3(N_/256),  dim3(256), 0, stream, gridp, ws);
  hipLaunchKernelGGL(k_gath,     dim3(NC_/256), dim3(256), 0, stream, imf, gridp, ws);
  hipLaunchKernelGGL(k_lin1,     dim3(N_/64),   dim3(64),  0, stream, pf, gridp, Wk, bk, Wfc, bfc, ws);
  hipLaunchKernelGGL(k_red2,     dim3(1),       dim3(256), 0, stream, gk, betak, gfc, betafc, ws);
  hipLaunchKernelGGL(k_qstage,   dim3(N_/64),   dim3(64),  0, stream, Wt, bt, Woff, boff, Wattn, battn, ws);
  hipLaunchKernelGGL(k_red1,     dim3(1),       dim3(256), 0, stream, gt, betat, ws, VAL_+16384, 200);
  hipLaunchKernelGGL(k_val,      dim3(HW_/256), dim3(256), 0, stream, imf, Wval, bval, ws);
  hipLaunchKernelGGL(k_knn2,     dim3(N_/64),   dim3(64),  0, stream, ws);
  hipLaunchKernelGGL(k_attn,     dim3(N_/64),   dim3(256), 0, stream, gridp, Wout, bout, Wf, bf, ws);
  hipLaunchKernelGGL(k_red1,     dim3(1),       dim3(256), 0, stream, gf, betaf, ws, PARTF_, 232);
  hipLaunchKernelGGL(k_out,      dim3(NC_/256), dim3(256), 0, stream, ws, out);
}

// Round 5
// 225.696 us; speedup vs baseline: 5.4607x; 1.2183x over previous
//
#include <hip/hip_runtime.h>
#include <climits>

#define N_ 16384
#define C_ 16
#define H_ 256
#define W_ 704
#define HW_ (H_*W_)
#define NC_ (N_*C_)
#define EPS_ 1e-3f
#define HDR_ 512

typedef unsigned long long ull;

// ---- workspace layout (float units) ----
// ints [0..5]: sum_y, sum_x, min_y, max_y, min_x, max_x
// [136..151] kA  [152..167] kC   [168..183] fcA [184..199] fcC
// [200..215] tA  [216..231] tC   [232..247] fA  [248..263] fC
// [264] cy [265] cx [266] inv_mx_y [267] inv_mx_x
// arrays at HDR_: pts_lin(0) pos_lin(1) gath(2) t_lin(3) off(4,5) attn(6) neigh(7) f_lin(8) val(9..)
// KNN int scratch after val: counts(180224) cellstart(180240) bsum(704) boff(704) psort(16384)
// partials: partK/partFC/partT live in the (not-yet-written) val region; partF after psort.

#define VAL_  (HDR_ + 9*NC_)
#define KNNI_ (VAL_ + HW_*16)
#define PARTF_ (KNNI_ + 378256)

__device__ __forceinline__ float wsum64(float v){
#pragma unroll
  for (int o = 32; o > 0; o >>= 1) v += __shfl_down(v, o);
  return v;
}

#define LOAD16(dst, src) { const float4* _s=(const float4*)(src); float4 _a=_s[0],_b=_s[1],_c=_s[2],_d=_s[3]; \
  dst[0]=_a.x;dst[1]=_a.y;dst[2]=_a.z;dst[3]=_a.w; dst[4]=_b.x;dst[5]=_b.y;dst[6]=_b.z;dst[7]=_b.w; \
  dst[8]=_c.x;dst[9]=_c.y;dst[10]=_c.z;dst[11]=_c.w; dst[12]=_d.x;dst[13]=_d.y;dst[14]=_d.z;dst[15]=_d.w; }

#define STORE16(dst, src) { float4* _d=(float4*)(dst); \
  _d[0]=make_float4(src[0],src[1],src[2],src[3]); _d[1]=make_float4(src[4],src[5],src[6],src[7]); \
  _d[2]=make_float4(src[8],src[9],src[10],src[11]); _d[3]=make_float4(src[12],src[13],src[14],src[15]); }

// zero cell counts + init header ints
__global__ __launch_bounds__(256) void k_init(float* ws){
  if (blockIdx.x < 176){
    int4* c = (int4*)(ws + KNNI_);
    c[blockIdx.x*256 + threadIdx.x] = make_int4(0,0,0,0);
  } else if (threadIdx.x == 0){
    int* ih = (int*)ws;
    ih[0]=0; ih[1]=0; ih[2]=INT_MAX; ih[3]=INT_MIN; ih[4]=INT_MAX; ih[5]=INT_MIN;
  }
}

// grid stats (block-level pre-reduction -> 6 atomics/block) + cell count
__global__ __launch_bounds__(256) void k_gridcnt(const int* __restrict__ grid, float* __restrict__ ws){
  int i = blockIdx.x*256 + threadIdx.x;
  int2 p = ((const int2*)grid)[i];
  int* counts = (int*)(ws + KNNI_);
  atomicAdd(&counts[p.x*W_ + p.y], 1);
  int sy=p.x, sx=p.y, mny=p.x, mxy=p.x, mnx=p.y, mxx=p.y;
#pragma unroll
  for (int o=32;o>0;o>>=1){
    sy += __shfl_down(sy,o); sx += __shfl_down(sx,o);
    mny = min(mny,__shfl_down(mny,o)); mxy = max(mxy,__shfl_down(mxy,o));
    mnx = min(mnx,__shfl_down(mnx,o)); mxx = max(mxx,__shfl_down(mxx,o));
  }
  __shared__ int sh[24];
  int w = threadIdx.x >> 6;
  if ((threadIdx.x & 63) == 0){
    sh[w]=sy; sh[4+w]=sx; sh[8+w]=mny; sh[12+w]=mxy; sh[16+w]=mnx; sh[20+w]=mxx;
  }
  __syncthreads();
  if (threadIdx.x == 0){
    int a0=sh[0]+sh[1]+sh[2]+sh[3];
    int a1=sh[4]+sh[5]+sh[6]+sh[7];
    int a2=min(min(sh[8],sh[9]),min(sh[10],sh[11]));
    int a3=max(max(sh[12],sh[13]),max(sh[14],sh[15]));
    int a4=min(min(sh[16],sh[17]),min(sh[18],sh[19]));
    int a5=max(max(sh[20],sh[21]),max(sh[22],sh[23]));
    int* ih = (int*)ws;
    atomicAdd(&ih[0],a0); atomicAdd(&ih[1],a1);
    atomicMin(&ih[2],a2); atomicMax(&ih[3],a3);
    atomicMin(&ih[4],a4); atomicMax(&ih[5],a5);
  }
}

__global__ __launch_bounds__(256) void k_scanA(float* ws){
  const int* counts = (const int*)(ws + KNNI_);
  int* bsum = (int*)(ws + KNNI_) + 180224 + 180240;
  int t = threadIdx.x;
  int v = counts[blockIdx.x*256 + t];
#pragma unroll
  for (int o=32;o>0;o>>=1) v += __shfl_down(v,o);
  __shared__ int w4[4];
  if ((t&63)==0) w4[t>>6] = v;
  __syncthreads();
  if (t==0) bsum[blockIdx.x] = w4[0]+w4[1]+w4[2]+w4[3];
}

// block-sum exclusive scan (+ grid center/scale finalize)
__global__ __launch_bounds__(256) void k_scanB(float* ws){
  if (threadIdx.x == 0){
    int* ih = (int*)ws;
    float cy = (float)ih[0] / (float)N_;
    float cx = (float)ih[1] / (float)N_;
    float my = fmaxf((float)ih[3]-cy, cy-(float)ih[2]);
    float mx = fmaxf((float)ih[5]-cx, cx-(float)ih[4]);
    if (my == 0.f) my = 1.f;
    if (mx == 0.f) mx = 1.f;
    ws[264]=cy; ws[265]=cx; ws[266]=1.f/my; ws[267]=1.f/mx;
  }
  int* bsum = (int*)(ws + KNNI_) + 180224 + 180240;
  int* boff = bsum + 704;
  __shared__ int tmp[256];
  __shared__ int carry;
  int t = threadIdx.x;
  if (t==0) carry = 0;
  __syncthreads();
  for (int c=0;c<3;++c){
    int idx = c*256 + t;
    int v = (idx < 704) ? bsum[idx] : 0;
    tmp[t] = v;
    __syncthreads();
    for (int o=1;o<256;o<<=1){
      int x = (t>=o) ? tmp[t-o] : 0;
      __syncthreads();
      tmp[t] += x;
      __syncthreads();
    }
    int incl = tmp[t];
    int base = carry;
    if (idx < 704) boff[idx] = base + incl - v;
    __syncthreads();
    if (t==255) carry = base + incl;
    __syncthreads();
  }
}

__global__ __launch_bounds__(256) void k_scanC(float* ws){
  int* counts = (int*)(ws + KNNI_);
  int* cellst = counts + 180224;
  const int* boff = counts + 180224 + 180240 + 704;
  __shared__ int tmp[256];
  int t = threadIdx.x;
  int i = blockIdx.x*256 + t;
  int v = counts[i];
  tmp[t] = v;
  __syncthreads();
  for (int o=1;o<256;o<<=1){
    int x = (t>=o) ? tmp[t-o] : 0;
    __syncthreads();
    tmp[t] += x;
    __syncthreads();
  }
  int start = boff[blockIdx.x] + tmp[t] - v;
  cellst[i] = start;
  counts[i] = start;          // becomes the scatter cursor
  if (i == 0) cellst[HW_] = N_;
}

__global__ __launch_bounds__(256) void k_scatter(const int* __restrict__ grid, float* __restrict__ ws){
  int i = blockIdx.x*256 + threadIdx.x;
  int2 g = ((const int2*)grid)[i];
  int* counts = (int*)(ws + KNNI_);
  unsigned* psort = (unsigned*)(counts + 180224 + 180240 + 704 + 704);
  int pos = atomicAdd(&counts[g.x*W_ + g.y], 1);
  psort[pos] = ((unsigned)g.x<<24) | ((unsigned)g.y<<14) | (unsigned)i;
}

// wide gather: one thread per (point, channel)
__global__ __launch_bounds__(256) void k_gath(const float* __restrict__ imf,
                                              const int* __restrict__ grid,
                                              float* __restrict__ ws){
  int idx = blockIdx.x*256 + threadIdx.x;   // 0..262143
  int i = idx >> 4, c = idx & 15;
  int2 g = ((const int2*)grid)[i];
  ws[HDR_ + 2*NC_ + idx] = imf[c*HW_ + g.x*W_ + g.y];
}

// exact KNN: 4 scanner lanes per point, LDS merge, block-uniform retry
__global__ __launch_bounds__(256) void k_knn3(float* __restrict__ ws){
  __shared__ ull sK[256*9];
  __shared__ int sNb[64*8];
  __shared__ int sR[64];
  __shared__ int sDoneP[64];
  __shared__ int sUndone;
  int tid = threadIdx.x;
  int s = tid & 3, pl = tid >> 2;
  int gid = blockIdx.x*64 + pl;
  const int* cellst = (const int*)(ws + KNNI_) + 180224;
  const unsigned* psort = (const unsigned*)((const int*)(ws + KNNI_) + 180224 + 180240 + 704 + 704);
  unsigned me = psort[gid];
  int y = (int)(me>>24), x = (int)((me>>14)&1023), i = (int)(me&16383);
  // pre-grow r near borders so the clipped box holds enough candidates
  int r = 8;
  for (;;){
    int y0=max(y-r,0), y1=min(y+r,H_-1), x0=max(x-r,0), x1=min(x+r,W_-1);
    bool covered = (y0==0)&&(y1==H_-1)&&(x0==0)&&(x1==W_-1);
    int area = (y1-y0+1)*(x1-x0+1);
    if (area >= 224 || covered) break;
    r += 8;
  }
  if (s == 0){ sR[pl] = r; sDoneP[pl] = 0; }
  if (tid == 0) sUndone = 0;
  __syncthreads();
  for (;;){
    r = sR[pl];
    bool active = (sDoneP[pl] == 0);
    int y0=max(y-r,0), y1=min(y+r,H_-1), x0=max(x-r,0), x1=min(x+r,W_-1);
    ull arr[9];
#pragma unroll
    for (int q=0;q<9;++q) arr[q] = ~0ull;
    if (active){
      for (int yy=y0+s; yy<=y1; yy+=4){
        int rowb = yy*W_;
        int st = cellst[rowb + x0];
        int e  = cellst[rowb + x1 + 1];
        for (int p=st; p<e; ++p){
          unsigned u = psort[p];
          int py = (int)(u>>24), px = (int)((u>>14)&1023), pi = (int)(u&16383);
          int dy = y-py, dx = x-px;
          int d2 = dy*dy + dx*dx;
          ull key = ((ull)(unsigned)d2 << 14) | (unsigned)pi;
          if (key < arr[8]){
            int q = 8;
            while (q > 0 && arr[q-1] > key){ arr[q] = arr[q-1]; --q; }
            arr[q] = key;
          }
        }
      }
#pragma unroll
      for (int q=0;q<9;++q) sK[tid*9+q] = arr[q];
    }
    __syncthreads();
    if (active && s == 0){
      for (int ss=1; ss<4; ++ss){
        for (int q2=0; q2<9; ++q2){
          ull k = sK[(tid+ss)*9+q2];
          if (k >= arr[8]) break;   // partner lists sorted ascending
          int q = 8;
          while (q > 0 && arr[q-1] > k){ arr[q] = arr[q-1]; --q; }
          arr[q] = k;
        }
      }
      bool covered = (y0==0)&&(y1==H_-1)&&(x0==0)&&(x1==W_-1);
      bool ok = covered;
      if (!ok && arr[8] != ~0ull){
        int d9 = (int)(arr[8] >> 14);
        ok = d9 < (r+1)*(r+1);
      }
      if (ok){
        sDoneP[pl] = 1;
#pragma unroll
        for (int q=1;q<9;++q) sNb[pl*8 + q-1] = (int)(arr[q] & 16383ull);
      } else {
        sR[pl] = r << 1;
        atomicAdd(&sUndone, 1);
      }
    }
    __syncthreads();
    int undone = sUndone;
    __syncthreads();
    if (undone == 0) break;
    if (tid == 0) sUndone = 0;
    // sUndone reset is ordered before next-iteration atomics by the scan-phase barrier
  }
  // fused neighbor-feature mean: 4 lanes x 4 floats
  const float* gath = ws + HDR_ + 2*NC_;
  float4 acc = make_float4(0.f,0.f,0.f,0.f);
#pragma unroll
  for (int nb=0; nb<8; ++nb){
    const float4 g = *(const float4*)(gath + sNb[pl*8+nb]*16 + s*4);
    acc.x += g.x; acc.y += g.y; acc.z += g.z; acc.w += g.w;
  }
  float* neigh = ws + HDR_ + 7*NC_;
  *(float4*)(neigh + i*16 + s*4) =
      make_float4(acc.x*0.125f, acc.y*0.125f, acc.z*0.125f, acc.w*0.125f);
}

__global__ __launch_bounds__(64) void k_lin1(
    const float* __restrict__ pf, const int* __restrict__ grid,
    const float* __restrict__ Wk, const float* __restrict__ bk,
    const float* __restrict__ Wfc, const float* __restrict__ bfc,
    float* __restrict__ ws)
{
  __shared__ float sWk[256], sbk[16], sWfc[32], sbfc[16];
  int t = threadIdx.x;
  for (int j=t;j<256;j+=64) sWk[j] = Wk[j];
  if (t < 16){ sbk[t]=bk[t]; sbfc[t]=bfc[t]; }
  if (t < 32) sWfc[t] = Wfc[t];
  __syncthreads();
  int i = blockIdx.x*64 + t;
  float p[16]; LOAD16(p, pf + i*16);
  float ok[16];
#pragma unroll
  for (int c=0;c<16;++c) ok[c] = sbk[c];
#pragma unroll
  for (int j=0;j<16;++j){ float v = p[j];
#pragma unroll
    for (int c=0;c<16;++c) ok[c] += v*sWk[j*16+c];
  }
  float* pts_lin = ws + HDR_;
  STORE16(pts_lin + i*16, ok);
  float cy=ws[264], cx=ws[265], imy=ws[266], imx=ws[267];
  int2 g = ((const int2*)grid)[i];
  float ry = ((float)g.x - cy)*imy, rx = ((float)g.y - cx)*imx;
  float op[16];
#pragma unroll
  for (int c=0;c<16;++c) op[c] = ry*sWfc[c] + rx*sWfc[16+c] + sbfc[c];
  float* pos_lin = ws + HDR_ + NC_;
  STORE16(pos_lin + i*16, op);
  float* partK  = ws + VAL_;
  float* partFC = ws + VAL_ + 8192;
#pragma unroll
  for (int c=0;c<16;++c){
    float a = wsum64(ok[c]); float b = wsum64(ok[c]*ok[c]);
    if (t==0){ partK[blockIdx.x*32+c]=a; partK[blockIdx.x*32+16+c]=b; }
    a = wsum64(op[c]); b = wsum64(op[c]*op[c]);
    if (t==0){ partFC[blockIdx.x*32+c]=a; partFC[blockIdx.x*32+16+c]=b; }
  }
}

// reduce 256x32 partials -> BN affine coefs (fuses bnfin)
__device__ __forceinline__ void red1_body(const float* __restrict__ g, const float* __restrict__ b,
                                          float* __restrict__ ws, int partOff, int aOff, float* red){
  int t = threadIdx.x, slot = t & 31, chunk = t >> 5;
  const float* part = ws + partOff;
  float acc = 0.f;
  for (int bb=chunk*32; bb<chunk*32+32; ++bb) acc += part[bb*32 + slot];
  red[t] = acc;
  __syncthreads();
  if (chunk == 0){
    float v = red[slot];
#pragma unroll
    for (int k2=1;k2<8;++k2) v += red[k2*32+slot];
    red[slot] = v;
  }
  __syncthreads();
  if (t < 16){
    float mu  = red[t]    * (1.f/N_);
    float var = red[16+t] * (1.f/N_) - mu*mu;
    float a = g[t] / sqrtf(var + EPS_);
    ws[aOff+t]    = a;
    ws[aOff+16+t] = b[t] - mu*a;
  }
  __syncthreads();
}

__global__ __launch_bounds__(256) void k_red2(const float* __restrict__ gk, const float* __restrict__ betak,
                                              const float* __restrict__ gfc, const float* __restrict__ betafc,
                                              float* __restrict__ ws){
  __shared__ float red[256];
  red1_body(gk, betak, ws, VAL_, 136, red);
  red1_body(gfc, betafc, ws, VAL_+8192, 168, red);
}

__global__ __launch_bounds__(256) void k_red1(const float* __restrict__ g, const float* __restrict__ b,
                                              float* __restrict__ ws, int partOff, int aOff){
  __shared__ float red[256];
  red1_body(g, b, ws, partOff, aOff, red);
}

__global__ __launch_bounds__(64) void k_qstage(
    const float* __restrict__ Wt, const float* __restrict__ bt,
    const float* __restrict__ Woff, const float* __restrict__ boff,
    const float* __restrict__ Wattn, const float* __restrict__ battn,
    float* __restrict__ ws)
{
  __shared__ float sWt[256], sWoff[512], sWattn[256];
  __shared__ float sbt[16], sboff[32], sbattn[16];
  __shared__ float skA[16], skC[16], sfcA[16], sfcC[16];
  int t = threadIdx.x;
  for (int j=t;j<256;j+=64){ sWt[j]=Wt[j]; sWattn[j]=Wattn[j]; }
  for (int j=t;j<512;j+=64) sWoff[j]=Woff[j];
  if (t<16){ sbt[t]=bt[t]; sbattn[t]=battn[t];
    skA[t]=ws[136+t]; skC[t]=ws[152+t]; sfcA[t]=ws[168+t]; sfcC[t]=ws[184+t]; }
  if (t<32) sboff[t]=boff[t];
  __syncthreads();
  int i = blockIdx.x*64 + t;
  float* pts_lin = ws + HDR_;
  float* pos_lin = ws + HDR_ + NC_;
  float* t_lin   = ws + HDR_ + 3*NC_;
  float* offp    = ws + HDR_ + 4*NC_;
  float* attnp   = ws + HDR_ + 6*NC_;
  float pl[16], po[16];
  LOAD16(pl, pts_lin + i*16);
  LOAD16(po, pos_lin + i*16);
  float pts[16], q[16];
#pragma unroll
  for (int c=0;c<16;++c){ pts[c] = pl[c]*skA[c]+skC[c]; q[c] = pts[c] + po[c]*sfcA[c]+sfcC[c]; }
  float tv[16];
#pragma unroll
  for (int c=0;c<16;++c) tv[c] = sbt[c];
#pragma unroll
  for (int j=0;j<16;++j){ float v=pts[j];
#pragma unroll
    for (int c=0;c<16;++c) tv[c] += v*sWt[j*16+c];
  }
  STORE16(t_lin + i*16, tv);
  float* partT = ws + VAL_ + 16384;
#pragma unroll
  for (int c=0;c<16;++c){
    float a = wsum64(tv[c]); float b = wsum64(tv[c]*tv[c]);
    if (t==0){ partT[blockIdx.x*32+c]=a; partT[blockIdx.x*32+16+c]=b; }
  }
  float ov[32];
#pragma unroll
  for (int o=0;o<32;++o) ov[o] = sboff[o];
#pragma unroll
  for (int j=0;j<16;++j){ float v=q[j];
#pragma unroll
    for (int o=0;o<32;++o) ov[o] += v*sWoff[j*32+o];
  }
  { float4* d=(float4*)(offp + i*32);
#pragma unroll
    for (int r=0;r<8;++r) d[r]=make_float4(ov[r*4],ov[r*4+1],ov[r*4+2],ov[r*4+3]);
  }
  float l[16];
#pragma unroll
  for (int c=0;c<16;++c) l[c] = sbattn[c];
#pragma unroll
  for (int j=0;j<16;++j){ float v=q[j];
#pragma unroll
    for (int c=0;c<16;++c) l[c] += v*sWattn[j*16+c];
  }
  float av[16];
#pragma unroll
  for (int h=0;h<4;++h){
    float m = fmaxf(fmaxf(l[h*4],l[h*4+1]),fmaxf(l[h*4+2],l[h*4+3]));
    float e0=expf(l[h*4]-m), e1=expf(l[h*4+1]-m), e2=expf(l[h*4+2]-m), e3=expf(l[h*4+3]-m);
    float inv = 1.f/(e0+e1+e2+e3);
    av[h*4]=e0*inv; av[h*4+1]=e1*inv; av[h*4+2]=e2*inv; av[h*4+3]=e3*inv;
  }
  STORE16(attnp + i*16, av);
}

__global__ __launch_bounds__(256) void k_val(const float* __restrict__ imf,
    const float* __restrict__ Wval, const float* __restrict__ bval, float* __restrict__ ws)
{
  __shared__ float sW[256], sb[16];
  int t = threadIdx.x;
  sW[t] = Wval[t];
  if (t < 16) sb[t] = bval[t];
  __syncthreads();
  int pix = blockIdx.x*256 + t;
  float a[16];
#pragma unroll
  for (int ci=0;ci<16;++ci) a[ci] = imf[ci*HW_ + pix];
  float o[16];
#pragma unroll
  for (int c=0;c<16;++c) o[c] = sb[c];
#pragma unroll
  for (int ci=0;ci<16;++ci){ float v=a[ci];
#pragma unroll
    for (int c=0;c<16;++c) o[c] += v*sW[ci*16+c];
  }
  float* val = ws + VAL_;
  STORE16(val + pix*16, o);
}

// deformable attn + Wout + fuse matmul + f-stats; (point, head) parallelism, 64 pts/block
__global__ __launch_bounds__(256) void k_attn(
    const int* __restrict__ grid,
    const float* __restrict__ Wout, const float* __restrict__ bout,
    const float* __restrict__ Wf, const float* __restrict__ bf,
    float* __restrict__ ws)
{
  __shared__ float sWout[256], sWf[512], sbout[16], sbf[16];
  __shared__ float sTl[1024], sNei[1024], sSamp[1024], sImg[1024];
  __shared__ float sPart[128];
  int t = threadIdx.x;
  int p = t >> 2, h = t & 3;
  int i = blockIdx.x*64 + p;
  sWout[t]=Wout[t]; sWf[t]=Wf[t]; sWf[t+256]=Wf[t+256];
  if (t<16){ sbout[t]=bout[t]; sbf[t]=bf[t]; }
  {
    const float4* tl4 = (const float4*)(ws + HDR_ + 3*NC_ + blockIdx.x*1024);
    const float4* nv4 = (const float4*)(ws + HDR_ + 7*NC_ + blockIdx.x*1024);
    float4 v = tl4[t];
    int c0 = (t*4) & 15;
    float a0=ws[200+c0],a1=ws[200+c0+1],a2=ws[200+c0+2],a3=ws[200+c0+3];
    float c0v=ws[216+c0],c1v=ws[216+c0+1],c2v=ws[216+c0+2],c3v=ws[216+c0+3];
    sTl[t*4]   = fmaxf(v.x*a0+c0v, 0.f);
    sTl[t*4+1] = fmaxf(v.y*a1+c1v, 0.f);
    sTl[t*4+2] = fmaxf(v.z*a2+c2v, 0.f);
    sTl[t*4+3] = fmaxf(v.w*a3+c3v, 0.f);
    float4 nv = nv4[t];
    sNei[t*4]=nv.x; sNei[t*4+1]=nv.y; sNei[t*4+2]=nv.z; sNei[t*4+3]=nv.w;
  }
  const float4* off4 = (const float4*)(ws + HDR_ + 4*NC_ + blockIdx.x*2048);
  float4 o0 = off4[t*2], o1 = off4[t*2+1];
  float4 aw = ((const float4*)(ws + HDR_ + 6*NC_ + blockIdx.x*1024))[t];
  int2 g = ((const int2*)grid)[i];
  float y = (float)g.x, x = (float)g.y;
  const float4* val4 = (const float4*)(ws + VAL_);
  float4 acc = make_float4(0.f,0.f,0.f,0.f);
  float offv[8] = {o0.x,o0.y,o0.z,o0.w,o1.x,o1.y,o1.z,o1.w};
  float avv[4]  = {aw.x,aw.y,aw.z,aw.w};
#define CORNER(yy,xx,wgt) do{ int _y=(yy),_x=(xx); \
    if ((unsigned)_y < (unsigned)H_ && (unsigned)_x < (unsigned)W_){ \
      float4 _v = val4[(_y*W_+_x)*4 + h]; float _w = a*(wgt); \
      acc.x += _w*_v.x; acc.y += _w*_v.y; acc.z += _w*_v.z; acc.w += _w*_v.w; } }while(0)
#pragma unroll
  for (int pt=0; pt<4; ++pt){
    float a  = avv[pt];
    float ly = y + offv[pt*2], lx = x + offv[pt*2+1];
    float fy = floorf(ly), fx = floorf(lx);
    float wy = ly - fy, wx = lx - fx;
    int y0 = (int)fy, x0 = (int)fx;
    CORNER(y0,   x0,   (1.f-wy)*(1.f-wx));
    CORNER(y0,   x0+1, (1.f-wy)*wx);
    CORNER(y0+1, x0,   wy*(1.f-wx));
    CORNER(y0+1, x0+1, wy*wx);
  }
#undef CORNER
  ((float4*)sSamp)[t] = acc;
  __syncthreads();
  float img[4];
#pragma unroll
  for (int k=0;k<4;++k){ int cc=h*4+k; img[k] = sbout[cc] + sNei[p*16+cc]; }
#pragma unroll
  for (int j=0;j<16;++j){
    float v = sSamp[p*16+j];
#pragma unroll
    for (int k=0;k<4;++k) img[k] += v*sWout[j*16 + h*4 + k];
  }
  ((float4*)sImg)[t] = make_float4(img[0],img[1],img[2],img[3]);
  __syncthreads();
  float fl[4];
#pragma unroll
  for (int k=0;k<4;++k) fl[k] = sbf[h*4+k];
#pragma unroll
  for (int j=0;j<16;++j){
    float v1 = sTl[p*16+j];
    float v2 = fmaxf(sImg[p*16+j], 0.f);
#pragma unroll
    for (int k=0;k<4;++k){
      fl[k] += v1*sWf[j*16 + h*4 + k];
      fl[k] += v2*sWf[(16+j)*16 + h*4 + k];
    }
  }
  float* f_lin = ws + HDR_ + 8*NC_;
  ((float4*)(f_lin + blockIdx.x*1024))[t] = make_float4(fl[0],fl[1],fl[2],fl[3]);
  float s0=fl[0],s1=fl[1],s2=fl[2],s3=fl[3];
  float q0=fl[0]*fl[0],q1=fl[1]*fl[1],q2=fl[2]*fl[2],q3=fl[3]*fl[3];
#pragma unroll
  for (int o=32;o>=4;o>>=1){
    s0+=__shfl_down(s0,o); s1+=__shfl_down(s1,o); s2+=__shfl_down(s2,o); s3+=__shfl_down(s3,o);
    q0+=__shfl_down(q0,o); q1+=__shfl_down(q1,o); q2+=__shfl_down(q2,o); q3+=__shfl_down(q3,o);
  }
  int wave = t >> 6, lane = t & 63;
  if (lane < 4){
    sPart[wave*32 + lane*4+0]=s0; sPart[wave*32 + lane*4+1]=s1;
    sPart[wave*32 + lane*4+2]=s2; sPart[wave*32 + lane*4+3]=s3;
    sPart[wave*32 + 16 + lane*4+0]=q0; sPart[wave*32 + 16 + lane*4+1]=q1;
    sPart[wave*32 + 16 + lane*4+2]=q2; sPart[wave*32 + 16 + lane*4+3]=q3;
  }
  __syncthreads();
  if (t < 32){
    float v = sPart[t]+sPart[32+t]+sPart[64+t]+sPart[96+t];
    (ws + PARTF_)[blockIdx.x*32 + t] = v;
  }
}

__global__ __launch_bounds__(256) void k_out(const float* __restrict__ ws, float* __restrict__ out){
  int idx = blockIdx.x*256 + threadIdx.x;
  int c = idx & 15;
  float v = ws[HDR_ + 8*NC_ + idx];
  out[idx] = fmaxf(v*ws[232+c] + ws[248+c], 0.f);
}

extern "C" void kernel_launch(void* const* d_in, const int* in_sizes, int n_in,
                              void* d_out, int out_size, void* d_ws, size_t ws_size,
                              hipStream_t stream)
{
  const float* pf    = (const float*)d_in[0];
  const float* imf   = (const float*)d_in[1];
  const int*   gridp = (const int*)d_in[2];
  const float* Wk   =(const float*)d_in[3],  *bk   =(const float*)d_in[4];
  const float* gk   =(const float*)d_in[5],  *betak=(const float*)d_in[6];
  const float* Wfc  =(const float*)d_in[7],  *bfc  =(const float*)d_in[8];
  const float* gfc  =(const float*)d_in[9],  *betafc=(const float*)d_in[10];
  const float* Wt   =(const float*)d_in[11], *bt   =(const float*)d_in[12];
  const float* gt   =(const float*)d_in[13], *betat=(const float*)d_in[14];
  const float* Woff =(const float*)d_in[15], *boff =(const float*)d_in[16];
  const float* Wattn=(const float*)d_in[17], *battn=(const float*)d_in[18];
  const float* Wval =(const float*)d_in[19], *bval =(const float*)d_in[20];
  const float* Wout =(const float*)d_in[21], *bout =(const float*)d_in[22];
  const float* Wf   =(const float*)d_in[23], *bf   =(const float*)d_in[24];
  const float* gf   =(const float*)d_in[25], *betaf=(const float*)d_in[26];
  float* ws  = (float*)d_ws;
  float* out = (float*)d_out;

  hipLaunchKernelGGL(k_init,     dim3(177),     dim3(256), 0, stream, ws);
  hipLaunchKernelGGL(k_gridcnt,  dim3(N_/256),  dim3(256), 0, stream, gridp, ws);
  hipLaunchKernelGGL(k_scanA,    dim3(704),     dim3(256), 0, stream, ws);
  hipLaunchKernelGGL(k_scanB,    dim3(1),       dim3(256), 0, stream, ws);
  hipLaunchKernelGGL(k_scanC,    dim3(704),     dim3(256), 0, stream, ws);
  hipLaunchKernelGGL(k_scatter,  dim3(N_/256),  dim3(256), 0, stream, gridp, ws);
  hipLaunchKernelGGL(k_gath,     dim3(NC_/256), dim3(256), 0, stream, imf, gridp, ws);
  hipLaunchKernelGGL(k_lin1,     dim3(N_/64),   dim3(64),  0, stream, pf, gridp, Wk, bk, Wfc, bfc, ws);
  hipLaunchKernelGGL(k_red2,     dim3(1),       dim3(256), 0, stream, gk, betak, gfc, betafc, ws);
  hipLaunchKernelGGL(k_qstage,   dim3(N_/64),   dim3(64),  0, stream, Wt, bt, Woff, boff, Wattn, battn, ws);
  hipLaunchKernelGGL(k_red1,     dim3(1),       dim3(256), 0, stream, gt, betat, ws, VAL_+16384, 200);
  hipLaunchKernelGGL(k_val,      dim3(HW_/256), dim3(256), 0, stream, imf, Wval, bval, ws);
  hipLaunchKernelGGL(k_knn3,     dim3(N_/64),   dim3(256), 0, stream, ws);
  hipLaunchKernelGGL(k_attn,     dim3(N_/64),   dim3(256), 0, stream, gridp, Wout, bout, Wf, bf, ws);
  hipLaunchKernelGGL(k_red1,     dim3(1),       dim3(256), 0, stream, gf, betaf, ws, PARTF_, 232);
  hipLaunchKernelGGL(k_out,      dim3(NC_/256), dim3(256), 0, stream, ws, out);
}

// Round 6
// 223.044 us; speedup vs baseline: 5.5256x; 1.0119x over previous
//
#include <hip/hip_runtime.h>
#include <climits>

#define N_ 16384
#define C_ 16
#define H_ 256
#define W_ 704
#define HW_ (H_*W_)
#define NC_ (N_*C_)
#define EPS_ 1e-3f
#define HDR_ 512

typedef unsigned long long ull;

// ---- workspace layout (float units) ----
// ints [0..5]: sum_y, sum_x, min_y, max_y, min_x, max_x
// [136..151] kA  [152..167] kC   [168..183] fcA [184..199] fcC
// [200..215] tA  [216..231] tC   [232..247] fA  [248..263] fC
// [264] cy [265] cx [266] inv_mx_y [267] inv_mx_x
// arrays at HDR_: pts_lin(0) pos_lin(1) gath(2) t_lin(3) off(4,5) attn(6) neigh(7) f_lin(8) val(9..)
// KNN int scratch after val: counts(180224) cellstart(180240) bsum(704) boff(704) psort(16384)
// BN partials: partF at PARTF_, partK/partFC/partT after it (NOT in val region).

#define VAL_   (HDR_ + 9*NC_)
#define KNNI_  (VAL_ + HW_*16)
#define PARTF_ (KNNI_ + 378256)
#define PK_    (PARTF_ + 8192)
#define PFC_   (PARTF_ + 16384)
#define PT_    (PARTF_ + 24576)

#define CAP_ 6144

__device__ __forceinline__ float wsum64(float v){
#pragma unroll
  for (int o = 32; o > 0; o >>= 1) v += __shfl_down(v, o);
  return v;
}

#define LOAD16(dst, src) { const float4* _s=(const float4*)(src); float4 _a=_s[0],_b=_s[1],_c=_s[2],_d=_s[3]; \
  dst[0]=_a.x;dst[1]=_a.y;dst[2]=_a.z;dst[3]=_a.w; dst[4]=_b.x;dst[5]=_b.y;dst[6]=_b.z;dst[7]=_b.w; \
  dst[8]=_c.x;dst[9]=_c.y;dst[10]=_c.z;dst[11]=_c.w; dst[12]=_d.x;dst[13]=_d.y;dst[14]=_d.z;dst[15]=_d.w; }

#define STORE16(dst, src) { float4* _d=(float4*)(dst); \
  _d[0]=make_float4(src[0],src[1],src[2],src[3]); _d[1]=make_float4(src[4],src[5],src[6],src[7]); \
  _d[2]=make_float4(src[8],src[9],src[10],src[11]); _d[3]=make_float4(src[12],src[13],src[14],src[15]); }

// zero cell counts + init header ints
__global__ __launch_bounds__(256) void k_init(float* ws){
  if (blockIdx.x < 176){
    int4* c = (int4*)(ws + KNNI_);
    c[blockIdx.x*256 + threadIdx.x] = make_int4(0,0,0,0);
  } else if (threadIdx.x == 0){
    int* ih = (int*)ws;
    ih[0]=0; ih[1]=0; ih[2]=INT_MAX; ih[3]=INT_MIN; ih[4]=INT_MAX; ih[5]=INT_MIN;
  }
}

// grid stats (block-level pre-reduction -> 6 atomics/block) + cell count
__global__ __launch_bounds__(256) void k_gridcnt(const int* __restrict__ grid, float* __restrict__ ws){
  int i = blockIdx.x*256 + threadIdx.x;
  int2 p = ((const int2*)grid)[i];
  int* counts = (int*)(ws + KNNI_);
  atomicAdd(&counts[p.x*W_ + p.y], 1);
  int sy=p.x, sx=p.y, mny=p.x, mxy=p.x, mnx=p.y, mxx=p.y;
#pragma unroll
  for (int o=32;o>0;o>>=1){
    sy += __shfl_down(sy,o); sx += __shfl_down(sx,o);
    mny = min(mny,__shfl_down(mny,o)); mxy = max(mxy,__shfl_down(mxy,o));
    mnx = min(mnx,__shfl_down(mnx,o)); mxx = max(mxx,__shfl_down(mxx,o));
  }
  __shared__ int sh[24];
  int w = threadIdx.x >> 6;
  if ((threadIdx.x & 63) == 0){
    sh[w]=sy; sh[4+w]=sx; sh[8+w]=mny; sh[12+w]=mxy; sh[16+w]=mnx; sh[20+w]=mxx;
  }
  __syncthreads();
  if (threadIdx.x == 0){
    int a0=sh[0]+sh[1]+sh[2]+sh[3];
    int a1=sh[4]+sh[5]+sh[6]+sh[7];
    int a2=min(min(sh[8],sh[9]),min(sh[10],sh[11]));
    int a3=max(max(sh[12],sh[13]),max(sh[14],sh[15]));
    int a4=min(min(sh[16],sh[17]),min(sh[18],sh[19]));
    int a5=max(max(sh[20],sh[21]),max(sh[22],sh[23]));
    int* ih = (int*)ws;
    atomicAdd(&ih[0],a0); atomicAdd(&ih[1],a1);
    atomicMin(&ih[2],a2); atomicMax(&ih[3],a3);
    atomicMin(&ih[4],a4); atomicMax(&ih[5],a5);
  }
}

__global__ __launch_bounds__(256) void k_scanA(float* ws){
  const int* counts = (const int*)(ws + KNNI_);
  int* bsum = (int*)(ws + KNNI_) + 180224 + 180240;
  int t = threadIdx.x;
  int v = counts[blockIdx.x*256 + t];
#pragma unroll
  for (int o=32;o>0;o>>=1) v += __shfl_down(v,o);
  __shared__ int w4[4];
  if ((t&63)==0) w4[t>>6] = v;
  __syncthreads();
  if (t==0) bsum[blockIdx.x] = w4[0]+w4[1]+w4[2]+w4[3];
}

// block-sum exclusive scan via wave shuffles (+ grid center/scale finalize)
__global__ __launch_bounds__(256) void k_scanB(float* ws){
  if (threadIdx.x == 0){
    int* ih = (int*)ws;
    float cy = (float)ih[0] / (float)N_;
    float cx = (float)ih[1] / (float)N_;
    float my = fmaxf((float)ih[3]-cy, cy-(float)ih[2]);
    float mx = fmaxf((float)ih[5]-cx, cx-(float)ih[4]);
    if (my == 0.f) my = 1.f;
    if (mx == 0.f) mx = 1.f;
    ws[264]=cy; ws[265]=cx; ws[266]=1.f/my; ws[267]=1.f/mx;
  }
  int* bsum = (int*)(ws + KNNI_) + 180224 + 180240;
  int* boff = bsum + 704;
  __shared__ int sWsum[4];
  __shared__ int sCarry;
  int t = threadIdx.x, lane = t & 63, wv = t >> 6;
  if (t==0) sCarry = 0;
  __syncthreads();
  for (int c=0;c<3;++c){
    int idx = c*256 + t;
    int v0 = (idx < 704) ? bsum[idx] : 0;
    int v = v0;
#pragma unroll
    for (int o=1;o<64;o<<=1){ int xx=__shfl_up(v,o); if (lane>=o) v+=xx; }
    if (lane==63) sWsum[wv]=v;
    __syncthreads();
    int add = sCarry;
    for (int w2=0;w2<wv;++w2) add += sWsum[w2];
    if (idx < 704) boff[idx] = add + v - v0;
    __syncthreads();
    if (t==255) sCarry = add + v;
    __syncthreads();
  }
}

__global__ __launch_bounds__(256) void k_scanC(float* ws){
  int* counts = (int*)(ws + KNNI_);
  int* cellst = counts + 180224;
  const int* boff = counts + 180224 + 180240 + 704;
  __shared__ int sWsum[4];
  int t = threadIdx.x, lane = t & 63, wv = t >> 6;
  int i = blockIdx.x*256 + t;
  int v0 = counts[i], v = v0;
#pragma unroll
  for (int o=1;o<64;o<<=1){ int xx=__shfl_up(v,o); if (lane>=o) v+=xx; }
  if (lane==63) sWsum[wv]=v;
  __syncthreads();
  int add = boff[blockIdx.x];
  for (int w2=0;w2<wv;++w2) add += sWsum[w2];
  int start = add + v - v0;
  cellst[i] = start;
  counts[i] = start;          // becomes the scatter cursor
  if (i == 0) cellst[HW_] = N_;
}

__global__ __launch_bounds__(256) void k_scatter(const int* __restrict__ grid, float* __restrict__ ws){
  int i = blockIdx.x*256 + threadIdx.x;
  int2 g = ((const int2*)grid)[i];
  int* counts = (int*)(ws + KNNI_);
  unsigned* psort = (unsigned*)(counts + 180224 + 180240 + 704 + 704);
  int pos = atomicAdd(&counts[g.x*W_ + g.y], 1);
  psort[pos] = ((unsigned)g.x<<24) | ((unsigned)g.y<<14) | (unsigned)i;
}

// fused: wide per-(point,channel) gather (blocks 0..1023) + val projection (blocks 1024..1727)
__global__ __launch_bounds__(256) void k_prep(const float* __restrict__ imf,
                                              const int* __restrict__ grid,
                                              const float* __restrict__ Wval,
                                              const float* __restrict__ bval,
                                              float* __restrict__ ws){
  int t = threadIdx.x;
  if (blockIdx.x < 1024){
    int idx = blockIdx.x*256 + t;   // 0..262143
    int i = idx >> 4, c = idx & 15;
    int2 g = ((const int2*)grid)[i];
    ws[HDR_ + 2*NC_ + idx] = imf[c*HW_ + g.x*W_ + g.y];
  } else {
    __shared__ float sW[256], sb[16];
    sW[t] = Wval[t];
    if (t < 16) sb[t] = bval[t];
    __syncthreads();
    int pix = (blockIdx.x-1024)*256 + t;
    float a[16];
#pragma unroll
    for (int ci=0;ci<16;++ci) a[ci] = imf[ci*HW_ + pix];
    float o[16];
#pragma unroll
    for (int c=0;c<16;++c) o[c] = sb[c];
#pragma unroll
    for (int ci=0;ci<16;++ci){ float v=a[ci];
#pragma unroll
      for (int c=0;c<16;++c) o[c] += v*sW[ci*16+c];
    }
    float* val = ws + VAL_;
    STORE16(val + pix*16, o);
  }
}

__device__ __forceinline__ void knn_insert(ull* arr, ull key){
  if (key < arr[8]){
    int q = 8;
    while (q > 0 && arr[q-1] > key){ arr[q] = arr[q-1]; --q; }
    arr[q] = key;
  }
}

__device__ __forceinline__ void scan_rows_global(const int* __restrict__ cellst,
                                                 const unsigned* __restrict__ psort,
                                                 int y, int x, int s,
                                                 int y0, int y1, int x0, int x1, ull* arr){
  for (int yy=y0+s; yy<=y1; yy+=4){
    int rowb = yy*W_;
    int st = cellst[rowb + x0];
    int e  = cellst[rowb + x1 + 1];
    int dy = y-yy, dy2 = dy*dy;
    for (int p=st; p<e; ++p){
      unsigned u = psort[p];
      int px = (int)((u>>14)&1023);
      int dx = x-px;
      knn_insert(arr, ((ull)(unsigned)(dy2+dx*dx) << 14) | (ull)(u & 16383u));
    }
  }
}

// exact KNN: LDS row-band + 4 scanner lanes/point + shuffle merge; global fallback for retries
__global__ __launch_bounds__(256) void k_knn4(float* __restrict__ ws){
  const int* cellst = (const int*)(ws + KNNI_) + 180224;
  const unsigned* psort = (const unsigned*)((const int*)(ws + KNNI_) + 180224 + 180240 + 704 + 704);
  __shared__ unsigned sBand[CAP_];
  __shared__ int sRowBase[80];
  __shared__ int sMn, sMx;
  int tid = threadIdx.x, lane = tid & 63;
  int s = tid & 3, pl = tid >> 2;
  int gid = blockIdx.x*64 + pl;
  unsigned me = psort[gid];
  int y = (int)(me>>24), x = (int)((me>>14)&1023), i = (int)(me&16383);
  if (tid==0){ sMn = INT_MAX; sMx = -1; }
  __syncthreads();
  if (s==0){ atomicMin(&sMn, y); atomicMax(&sMx, y); }
  __syncthreads();
  int ya = max(sMn-16,0), yb = min(sMx+16,H_-1);
  int nr = yb-ya+1;
  int p0 = cellst[ya*W_], p1 = cellst[(yb+1)*W_];
  int count = p1-p0;
  bool fb = (count > CAP_) || (nr > 78);
  if (!fb){
    for (int j=tid; j<count; j+=256) sBand[j] = psort[p0+j];
    for (int j=tid; j<=nr; j+=256) sRowBase[j] = cellst[(ya+j)*W_] - p0;
  }
  __syncthreads();
  // pre-grow r (caps at 16: any clipped 17x17 box has area >= 289 >= 224)
  int r = 8;
  { int y0=max(y-8,0),y1=min(y+8,H_-1),x0=max(x-8,0),x1=min(x+8,W_-1);
    if ((y1-y0+1)*(x1-x0+1) < 224) r = 16; }
  ull arr[9];
#pragma unroll
  for (int q=0;q<9;++q) arr[q] = ~0ull;
  {
    int y0=max(y-r,0),y1=min(y+r,H_-1),x0=max(x-r,0),x1=min(x+r,W_-1);
    if (!fb){
      for (int yy=y0+s; yy<=y1; yy+=4){
        int j = yy-ya;
        int b = sRowBase[j], e = sRowBase[j+1];
        int lo=b, hi=e;
        while (lo<hi){ int mid=(lo+hi)>>1; int xm=(int)((sBand[mid]>>14)&1023); if (xm<x0) lo=mid+1; else hi=mid; }
        int dy = y-yy, dy2 = dy*dy;
        for (int p=lo; p<e; ++p){
          unsigned u = sBand[p];
          int px = (int)((u>>14)&1023);
          if (px > x1) break;
          int dx = x-px;
          knn_insert(arr, ((ull)(unsigned)(dy2+dx*dx) << 14) | (ull)(u & 16383u));
        }
      }
    } else {
      scan_rows_global(cellst, psort, y, x, s, y0, y1, x0, x1, arr);
    }
  }
  ull m[9];
  bool done = false;
  // first merge (uniform shuffles) + acceptance check
  {
    ull k[9];
#pragma unroll
    for (int q=0;q<9;++q) m[q] = ~0ull;
    int base = lane & ~3;
    for (int ss=0; ss<4; ++ss){
#pragma unroll
      for (int q=0;q<9;++q) k[q] = __shfl(arr[q], base+ss);
      for (int q2=0;q2<9;++q2){
        ull kk = k[q2];
        if (kk >= m[8]) break;
        int q = 8; while (q>0 && m[q-1]>kk){ m[q]=m[q-1]; --q; } m[q]=kk;
      }
    }
    int y0=max(y-r,0),y1=min(y+r,H_-1),x0=max(x-r,0),x1=min(x+r,W_-1);
    bool covered = (y0==0)&&(y1==H_-1)&&(x0==0)&&(x1==W_-1);
    bool ok = covered;
    if (!ok && m[8] != ~0ull){ int d9 = (int)(m[8]>>14); ok = d9 < (r+1)*(r+1); }
    done = ok;
  }
  // rare retries: wave-uniform loop, global scan, shuffle merge outside divergence
  while (__ballot(!done)){
    if (!done){
      r <<= 1;
      int y0=max(y-r,0),y1=min(y+r,H_-1),x0=max(x-r,0),x1=min(x+r,W_-1);
#pragma unroll
      for (int q=0;q<9;++q) arr[q] = ~0ull;
      scan_rows_global(cellst, psort, y, x, s, y0, y1, x0, x1, arr);
    }
    ull k[9];
    bool doIns = !done;
    if (doIns){
#pragma unroll
      for (int q=0;q<9;++q) m[q] = ~0ull;
    }
    int base = lane & ~3;
    for (int ss=0; ss<4; ++ss){
#pragma unroll
      for (int q=0;q<9;++q) k[q] = __shfl(arr[q], base+ss);
      if (doIns){
        for (int q2=0;q2<9;++q2){
          ull kk = k[q2];
          if (kk >= m[8]) break;
          int q = 8; while (q>0 && m[q-1]>kk){ m[q]=m[q-1]; --q; } m[q]=kk;
        }
      }
    }
    if (!done){
      int y0=max(y-r,0),y1=min(y+r,H_-1),x0=max(x-r,0),x1=min(x+r,W_-1);
      bool covered = (y0==0)&&(y1==H_-1)&&(x0==0)&&(x1==W_-1);
      bool ok = covered;
      if (!ok && m[8] != ~0ull){ int d9 = (int)(m[8]>>14); ok = d9 < (r+1)*(r+1); }
      if (ok) done = true;
    }
  }
  // fused neighbor-feature mean: all 4 lanes gather their float4 quarter (m identical across lanes)
  const float* gath = ws + HDR_ + 2*NC_;
  float4 acc = make_float4(0.f,0.f,0.f,0.f);
#pragma unroll
  for (int nb=1; nb<9; ++nb){
    int idx = (int)(m[nb] & 16383ull);
    const float4 g = *(const float4*)(gath + idx*16 + s*4);
    acc.x += g.x; acc.y += g.y; acc.z += g.z; acc.w += g.w;
  }
  float* neigh = ws + HDR_ + 7*NC_;
  *(float4*)(neigh + i*16 + s*4) =
      make_float4(acc.x*0.125f, acc.y*0.125f, acc.z*0.125f, acc.w*0.125f);
}

__global__ __launch_bounds__(64) void k_lin1(
    const float* __restrict__ pf, const int* __restrict__ grid,
    const float* __restrict__ Wk, const float* __restrict__ bk,
    const float* __restrict__ Wfc, const float* __restrict__ bfc,
    float* __restrict__ ws)
{
  __shared__ float sWk[256], sbk[16], sWfc[32], sbfc[16];
  int t = threadIdx.x;
  for (int j=t;j<256;j+=64) sWk[j] = Wk[j];
  if (t < 16){ sbk[t]=bk[t]; sbfc[t]=bfc[t]; }
  if (t < 32) sWfc[t] = Wfc[t];
  __syncthreads();
  int i = blockIdx.x*64 + t;
  float p[16]; LOAD16(p, pf + i*16);
  float ok[16];
#pragma unroll
  for (int c=0;c<16;++c) ok[c] = sbk[c];
#pragma unroll
  for (int j=0;j<16;++j){ float v = p[j];
#pragma unroll
    for (int c=0;c<16;++c) ok[c] += v*sWk[j*16+c];
  }
  float* pts_lin = ws + HDR_;
  STORE16(pts_lin + i*16, ok);
  float cy=ws[264], cx=ws[265], imy=ws[266], imx=ws[267];
  int2 g = ((const int2*)grid)[i];
  float ry = ((float)g.x - cy)*imy, rx = ((float)g.y - cx)*imx;
  float op[16];
#pragma unroll
  for (int c=0;c<16;++c) op[c] = ry*sWfc[c] + rx*sWfc[16+c] + sbfc[c];
  float* pos_lin = ws + HDR_ + NC_;
  STORE16(pos_lin + i*16, op);
  float* partK  = ws + PK_;
  float* partFC = ws + PFC_;
#pragma unroll
  for (int c=0;c<16;++c){
    float a = wsum64(ok[c]); float b = wsum64(ok[c]*ok[c]);
    if (t==0){ partK[blockIdx.x*32+c]=a; partK[blockIdx.x*32+16+c]=b; }
    a = wsum64(op[c]); b = wsum64(op[c]*op[c]);
    if (t==0){ partFC[blockIdx.x*32+c]=a; partFC[blockIdx.x*32+16+c]=b; }
  }
}

// reduce 256x32 partials -> BN affine coefs (fuses bnfin)
__device__ __forceinline__ void red1_body(const float* __restrict__ g, const float* __restrict__ b,
                                          float* __restrict__ ws, int partOff, int aOff, float* red){
  int t = threadIdx.x, slot = t & 31, chunk = t >> 5;
  const float* part = ws + partOff;
  float acc = 0.f;
  for (int bb=chunk*32; bb<chunk*32+32; ++bb) acc += part[bb*32 + slot];
  red[t] = acc;
  __syncthreads();
  if (chunk == 0){
    float v = red[slot];
#pragma unroll
    for (int k2=1;k2<8;++k2) v += red[k2*32+slot];
    red[slot] = v;
  }
  __syncthreads();
  if (t < 16){
    float mu  = red[t]    * (1.f/N_);
    float var = red[16+t] * (1.f/N_) - mu*mu;
    float a = g[t] / sqrtf(var + EPS_);
    ws[aOff+t]    = a;
    ws[aOff+16+t] = b[t] - mu*a;
  }
  __syncthreads();
}

__global__ __launch_bounds__(256) void k_red2(const float* __restrict__ gk, const float* __restrict__ betak,
                                              const float* __restrict__ gfc, const float* __restrict__ betafc,
                                              float* __restrict__ ws){
  __shared__ float red[256];
  red1_body(gk, betak, ws, PK_, 136, red);
  red1_body(gfc, betafc, ws, PFC_, 168, red);
}

__global__ __launch_bounds__(256) void k_red1(const float* __restrict__ g, const float* __restrict__ b,
                                              float* __restrict__ ws, int partOff, int aOff){
  __shared__ float red[256];
  red1_body(g, b, ws, partOff, aOff, red);
}

__global__ __launch_bounds__(64) void k_qstage(
    const float* __restrict__ Wt, const float* __restrict__ bt,
    const float* __restrict__ Woff, const float* __restrict__ boff,
    const float* __restrict__ Wattn, const float* __restrict__ battn,
    float* __restrict__ ws)
{
  __shared__ float sWt[256], sWoff[512], sWattn[256];
  __shared__ float sbt[16], sboff[32], sbattn[16];
  __shared__ float skA[16], skC[16], sfcA[16], sfcC[16];
  int t = threadIdx.x;
  for (int j=t;j<256;j+=64){ sWt[j]=Wt[j]; sWattn[j]=Wattn[j]; }
  for (int j=t;j<512;j+=64) sWoff[j]=Woff[j];
  if (t<16){ sbt[t]=bt[t]; sbattn[t]=battn[t];
    skA[t]=ws[136+t]; skC[t]=ws[152+t]; sfcA[t]=ws[168+t]; sfcC[t]=ws[184+t]; }
  if (t<32) sboff[t]=boff[t];
  __syncthreads();
  int i = blockIdx.x*64 + t;
  float* pts_lin = ws + HDR_;
  float* pos_lin = ws + HDR_ + NC_;
  float* t_lin   = ws + HDR_ + 3*NC_;
  float* offp    = ws + HDR_ + 4*NC_;
  float* attnp   = ws + HDR_ + 6*NC_;
  float pl[16], po[16];
  LOAD16(pl, pts_lin + i*16);
  LOAD16(po, pos_lin + i*16);
  float pts[16], q[16];
#pragma unroll
  for (int c=0;c<16;++c){ pts[c] = pl[c]*skA[c]+skC[c]; q[c] = pts[c] + po[c]*sfcA[c]+sfcC[c]; }
  float tv[16];
#pragma unroll
  for (int c=0;c<16;++c) tv[c] = sbt[c];
#pragma unroll
  for (int j=0;j<16;++j){ float v=pts[j];
#pragma unroll
    for (int c=0;c<16;++c) tv[c] += v*sWt[j*16+c];
  }
  STORE16(t_lin + i*16, tv);
  float* partT = ws + PT_;
#pragma unroll
  for (int c=0;c<16;++c){
    float a = wsum64(tv[c]); float b = wsum64(tv[c]*tv[c]);
    if (t==0){ partT[blockIdx.x*32+c]=a; partT[blockIdx.x*32+16+c]=b; }
  }
  float ov[32];
#pragma unroll
  for (int o=0;o<32;++o) ov[o] = sboff[o];
#pragma unroll
  for (int j=0;j<16;++j){ float v=q[j];
#pragma unroll
    for (int o=0;o<32;++o) ov[o] += v*sWoff[j*32+o];
  }
  { float4* d=(float4*)(offp + i*32);
#pragma unroll
    for (int r=0;r<8;++r) d[r]=make_float4(ov[r*4],ov[r*4+1],ov[r*4+2],ov[r*4+3]);
  }
  float l[16];
#pragma unroll
  for (int c=0;c<16;++c) l[c] = sbattn[c];
#pragma unroll
  for (int j=0;j<16;++j){ float v=q[j];
#pragma unroll
    for (int c=0;c<16;++c) l[c] += v*sWattn[j*16+c];
  }
  float av[16];
#pragma unroll
  for (int h=0;h<4;++h){
    float m = fmaxf(fmaxf(l[h*4],l[h*4+1]),fmaxf(l[h*4+2],l[h*4+3]));
    float e0=expf(l[h*4]-m), e1=expf(l[h*4+1]-m), e2=expf(l[h*4+2]-m), e3=expf(l[h*4+3]-m);
    float inv = 1.f/(e0+e1+e2+e3);
    av[h*4]=e0*inv; av[h*4+1]=e1*inv; av[h*4+2]=e2*inv; av[h*4+3]=e3*inv;
  }
  STORE16(attnp + i*16, av);
}

// deformable attn + Wout + fuse matmul + f-stats; (point, head) parallelism, 64 pts/block
__global__ __launch_bounds__(256) void k_attn(
    const int* __restrict__ grid,
    const float* __restrict__ Wout, const float* __restrict__ bout,
    const float* __restrict__ Wf, const float* __restrict__ bf,
    float* __restrict__ ws)
{
  __shared__ float sWout[256], sWf[512], sbout[16], sbf[16];
  __shared__ float sTl[1024], sNei[1024], sSamp[1024], sImg[1024];
  __shared__ float sPart[128];
  int t = threadIdx.x;
  int p = t >> 2, h = t & 3;
  int i = blockIdx.x*64 + p;
  sWout[t]=Wout[t]; sWf[t]=Wf[t]; sWf[t+256]=Wf[t+256];
  if (t<16){ sbout[t]=bout[t]; sbf[t]=bf[t]; }
  {
    const float4* tl4 = (const float4*)(ws + HDR_ + 3*NC_ + blockIdx.x*1024);
    const float4* nv4 = (const float4*)(ws + HDR_ + 7*NC_ + blockIdx.x*1024);
    float4 v = tl4[t];
    int c0 = (t*4) & 15;
    float a0=ws[200+c0],a1=ws[200+c0+1],a2=ws[200+c0+2],a3=ws[200+c0+3];
    float c0v=ws[216+c0],c1v=ws[216+c0+1],c2v=ws[216+c0+2],c3v=ws[216+c0+3];
    sTl[t*4]   = fmaxf(v.x*a0+c0v, 0.f);
    sTl[t*4+1] = fmaxf(v.y*a1+c1v, 0.f);
    sTl[t*4+2] = fmaxf(v.z*a2+c2v, 0.f);
    sTl[t*4+3] = fmaxf(v.w*a3+c3v, 0.f);
    float4 nv = nv4[t];
    sNei[t*4]=nv.x; sNei[t*4+1]=nv.y; sNei[t*4+2]=nv.z; sNei[t*4+3]=nv.w;
  }
  const float4* off4 = (const float4*)(ws + HDR_ + 4*NC_ + blockIdx.x*2048);
  float4 o0 = off4[t*2], o1 = off4[t*2+1];
  float4 aw = ((const float4*)(ws + HDR_ + 6*NC_ + blockIdx.x*1024))[t];
  int2 g = ((const int2*)grid)[i];
  float y = (float)g.x, x = (float)g.y;
  const float4* val4 = (const float4*)(ws + VAL_);
  float4 acc = make_float4(0.f,0.f,0.f,0.f);
  float offv[8] = {o0.x,o0.y,o0.z,o0.w,o1.x,o1.y,o1.z,o1.w};
  float avv[4]  = {aw.x,aw.y,aw.z,aw.w};
#define CORNER(yy,xx,wgt) do{ int _y=(yy),_x=(xx); \
    if ((unsigned)_y < (unsigned)H_ && (unsigned)_x < (unsigned)W_){ \
      float4 _v = val4[(_y*W_+_x)*4 + h]; float _w = a*(wgt); \
      acc.x += _w*_v.x; acc.y += _w*_v.y; acc.z += _w*_v.z; acc.w += _w*_v.w; } }while(0)
#pragma unroll
  for (int pt=0; pt<4; ++pt){
    float a  = avv[pt];
    float ly = y + offv[pt*2], lx = x + offv[pt*2+1];
    float fy = floorf(ly), fx = floorf(lx);
    float wy = ly - fy, wx = lx - fx;
    int y0 = (int)fy, x0 = (int)fx;
    CORNER(y0,   x0,   (1.f-wy)*(1.f-wx));
    CORNER(y0,   x0+1, (1.f-wy)*wx);
    CORNER(y0+1, x0,   wy*(1.f-wx));
    CORNER(y0+1, x0+1, wy*wx);
  }
#undef CORNER
  ((float4*)sSamp)[t] = acc;
  __syncthreads();
  float img[4];
#pragma unroll
  for (int k=0;k<4;++k){ int cc=h*4+k; img[k] = sbout[cc] + sNei[p*16+cc]; }
#pragma unroll
  for (int j=0;j<16;++j){
    float v = sSamp[p*16+j];
#pragma unroll
    for (int k=0;k<4;++k) img[k] += v*sWout[j*16 + h*4 + k];
  }
  ((float4*)sImg)[t] = make_float4(img[0],img[1],img[2],img[3]);
  __syncthreads();
  float fl[4];
#pragma unroll
  for (int k=0;k<4;++k) fl[k] = sbf[h*4+k];
#pragma unroll
  for (int j=0;j<16;++j){
    float v1 = sTl[p*16+j];
    float v2 = fmaxf(sImg[p*16+j], 0.f);
#pragma unroll
    for (int k=0;k<4;++k){
      fl[k] += v1*sWf[j*16 + h*4 + k];
      fl[k] += v2*sWf[(16+j)*16 + h*4 + k];
    }
  }
  float* f_lin = ws + HDR_ + 8*NC_;
  ((float4*)(f_lin + blockIdx.x*1024))[t] = make_float4(fl[0],fl[1],fl[2],fl[3]);
  float s0=fl[0],s1=fl[1],s2=fl[2],s3=fl[3];
  float q0=fl[0]*fl[0],q1=fl[1]*fl[1],q2=fl[2]*fl[2],q3=fl[3]*fl[3];
#pragma unroll
  for (int o=32;o>=4;o>>=1){
    s0+=__shfl_down(s0,o); s1+=__shfl_down(s1,o); s2+=__shfl_down(s2,o); s3+=__shfl_down(s3,o);
    q0+=__shfl_down(q0,o); q1+=__shfl_down(q1,o); q2+=__shfl_down(q2,o); q3+=__shfl_down(q3,o);
  }
  int wave = t >> 6, lane = t & 63;
  if (lane < 4){
    sPart[wave*32 + lane*4+0]=s0; sPart[wave*32 + lane*4+1]=s1;
    sPart[wave*32 + lane*4+2]=s2; sPart[wave*32 + lane*4+3]=s3;
    sPart[wave*32 + 16 + lane*4+0]=q0; sPart[wave*32 + 16 + lane*4+1]=q1;
    sPart[wave*32 + 16 + lane*4+2]=q2; sPart[wave*32 + 16 + lane*4+3]=q3;
  }
  __syncthreads();
  if (t < 32){
    float v = sPart[t]+sPart[32+t]+sPart[64+t]+sPart[96+t];
    (ws + PARTF_)[blockIdx.x*32 + t] = v;
  }
}

__global__ __launch_bounds__(256) void k_out(const float* __restrict__ ws, float* __restrict__ out){
  int idx = blockIdx.x*256 + threadIdx.x;
  int c = idx & 15;
  float v = ws[HDR_ + 8*NC_ + idx];
  out[idx] = fmaxf(v*ws[232+c] + ws[248+c], 0.f);
}

extern "C" void kernel_launch(void* const* d_in, const int* in_sizes, int n_in,
                              void* d_out, int out_size, void* d_ws, size_t ws_size,
                              hipStream_t stream)
{
  const float* pf    = (const float*)d_in[0];
  const float* imf   = (const float*)d_in[1];
  const int*   gridp = (const int*)d_in[2];
  const float* Wk   =(const float*)d_in[3],  *bk   =(const float*)d_in[4];
  const float* gk   =(const float*)d_in[5],  *betak=(const float*)d_in[6];
  const float* Wfc  =(const float*)d_in[7],  *bfc  =(const float*)d_in[8];
  const float* gfc  =(const float*)d_in[9],  *betafc=(const float*)d_in[10];
  const float* Wt   =(const float*)d_in[11], *bt   =(const float*)d_in[12];
  const float* gt   =(const float*)d_in[13], *betat=(const float*)d_in[14];
  const float* Woff =(const float*)d_in[15], *boff =(const float*)d_in[16];
  const float* Wattn=(const float*)d_in[17], *battn=(const float*)d_in[18];
  const float* Wval =(const float*)d_in[19], *bval =(const float*)d_in[20];
  const float* Wout =(const float*)d_in[21], *bout =(const float*)d_in[22];
  const float* Wf   =(const float*)d_in[23], *bf   =(const float*)d_in[24];
  const float* gf   =(const float*)d_in[25], *betaf=(const float*)d_in[26];
  float* ws  = (float*)d_ws;
  float* out = (float*)d_out;

  hipLaunchKernelGGL(k_init,     dim3(177),      dim3(256), 0, stream, ws);
  hipLaunchKernelGGL(k_gridcnt,  dim3(N_/256),   dim3(256), 0, stream, gridp, ws);
  hipLaunchKernelGGL(k_scanA,    dim3(704),      dim3(256), 0, stream, ws);
  hipLaunchKernelGGL(k_scanB,    dim3(1),        dim3(256), 0, stream, ws);
  hipLaunchKernelGGL(k_scanC,    dim3(704),      dim3(256), 0, stream, ws);
  hipLaunchKernelGGL(k_scatter,  dim3(N_/256),   dim3(256), 0, stream, gridp, ws);
  hipLaunchKernelGGL(k_prep,     dim3(1728),     dim3(256), 0, stream, imf, gridp, Wval, bval, ws);
  hipLaunchKernelGGL(k_lin1,     dim3(N_/64),    dim3(64),  0, stream, pf, gridp, Wk, bk, Wfc, bfc, ws);
  hipLaunchKernelGGL(k_red2,     dim3(1),        dim3(256), 0, stream, gk, betak, gfc, betafc, ws);
  hipLaunchKernelGGL(k_qstage,   dim3(N_/64),    dim3(64),  0, stream, Wt, bt, Woff, boff, Wattn, battn, ws);
  hipLaunchKernelGGL(k_red1,     dim3(1),        dim3(256), 0, stream, gt, betat, ws, PT_, 200);
  hipLaunchKernelGGL(k_knn4,     dim3(N_/64),    dim3(256), 0, stream, ws);
  hipLaunchKernelGGL(k_attn,     dim3(N_/64),    dim3(256), 0, stream, gridp, Wout, bout, Wf, bf, ws);
  hipLaunchKernelGGL(k_red1,     dim3(1),        dim3(256), 0, stream, gf, betaf, ws, PARTF_, 232);
  hipLaunchKernelGGL(k_out,      dim3(NC_/256),  dim3(256), 0, stream, ws, out);
}